// Round 11
// baseline (271.772 us; speedup 1.0000x reference)
//
#include <hip/hip_runtime.h>

// out[b,n] = sum_{c,hw} x[b,c,hw] * W_s[n,hw] * W_d[n,c] + W_b[n]
// B=512, C=384, N=512, HW=169 (13x13).
//
// R19: R18 falsified the VMEM-throughput theory (halving B-stream bytes
// changed nothing). R15-R18 all pin at ~102-106us with every pipe <15% busy
// and occupancy <=37.5% (3 waves/SIMD: ~112 unified regs -> (102,128] band).
// Latency-bound; buy WAVES by shrinking per-wave state:
//  - CT 64 (6 c_blks/b, grid 3072): wave owns ONE 16-c fragment.
//    a[6]=24 + bfr 24 + acc 4 + wdf 4 + addr ~25 = ~80 regs -> fits the
//    102-reg band: __launch_bounds__(256,5) = 62.5% occupancy (vs 37.5%).
//  - Loop: 6 bfr + 1 wdf load, 6 MFMA, fold, ONE shfl_xor(16) -> 8 red rows
//    (16.5 KB LDS, 5-block fit). Combine after the single barrier.
//  - 6 part slabs (6 MB) + reducer; no atomics; XCD swizzle keeps the 6
//    c_blks of one b on one XCD slot.
// Spill detector: WRITE_SIZE must stay ~6 MB. Occupancy check: ~55-62%.

#define B_   512
#define C_   384
#define N_   512
#define HW_  169
#define CT_P 64      // conv_part c-tile rows (6 c_blks per b)
#define CT   128     // v8/fallback c-tile rows
#define SXR  200     // Xs row stride (v8/fallback kernels)
#define RSTR 516     // red row stride in f32 (512 + 4 pad)

#define WSF_ELEMS  ((size_t)32 * 6 * 64 * 8)       // 98,304 bf16
#define WDF_ELEMS  ((size_t)24 * 32 * 64 * 4)      // 196,608 f32
#define PART_ELEMS ((size_t)6 * B_ * N_)           // 1,572,864 f32 (6 MB)

typedef __bf16 bf16x8 __attribute__((ext_vector_type(8)));
typedef float f32x4  __attribute__((ext_vector_type(4)));
typedef float f32x4u __attribute__((ext_vector_type(4), aligned(4)));
typedef unsigned u32x4 __attribute__((ext_vector_type(4)));

__device__ __forceinline__ __bf16 f2bf(float f) {
  union { float f; unsigned u; } v; v.f = f;
  unsigned r = (v.u + 0x7FFFu + ((v.u >> 16) & 1u)) >> 16;   // RNE
  unsigned short s = (unsigned short)r;
  return __builtin_bit_cast(__bf16, s);
}

// hi16(a)|hi16(b)<<16 : two bf16 truncations in one v_perm
__device__ __forceinline__ unsigned pack_trunc(float a, float b) {
  return __builtin_amdgcn_perm(__builtin_bit_cast(unsigned, b),
                               __builtin_bit_cast(unsigned, a), 0x07060302u);
}

// ---------------- prep_aux: wsf (B-frag order) + wdf (C-layout order) ----------------
__global__ __launch_bounds__(256)
void prep_aux_kernel(const float* __restrict__ Ws,
                     const float* __restrict__ Wd,
                     __bf16* __restrict__ wsf,
                     float* __restrict__ wdf) {
  int t = blockIdx.x * 256 + threadIdx.x;      // 61440 total, exact
  if (t < 12288) {
    // wsf: t = (nm*6 + kb)*64 + lane ; lane(q=l>>4,m=l&15) holds Ws[nm*16+m][kb*32+q*8+j]
    int lane = t & 63;
    int fr   = t >> 6;
    int kb   = fr % 6;
    int nm   = fr / 6;
    int n    = nm * 16 + (lane & 15);
    int k0   = kb * 32 + (lane >> 4) * 8;
    const float* src = Ws + (size_t)n * HW_;
    bf16x8 v;
    #pragma unroll
    for (int j = 0; j < 8; ++j) {
      int k = k0 + j;
      float f = (k < HW_) ? src[k] : 0.f;
      v[j] = f2bf(f);
    }
    *(bf16x8*)(wsf + (size_t)t * 8) = v;
  } else {
    // wdf: t2 = (cm*32 + nm)*64 + lane; elem i = Wd[nm*16+(l&15)][cm*16+(l>>4)*4+i]
    int t2 = t - 12288;
    int lane = t2 & 63;
    int fr   = t2 >> 6;
    int nm   = fr & 31;
    int cm   = fr >> 5;
    int n    = nm * 16 + (lane & 15);
    int c0   = cm * 16 + (lane >> 4) * 4;
    f32x4 w = *(const f32x4u*)(Wd + (size_t)n * C_ + c0);
    *(f32x4*)(wdf + (size_t)t2 * 4) = w;
  }
}

// ---------------- R19 main kernel: minimal per-wave state, 5 waves/SIMD ----------------
__global__ __launch_bounds__(256, 5)       // ~80 regs -> 102-reg band
void conv_part(const float* __restrict__ x,
               const __bf16* __restrict__ wsf,
               const float* __restrict__ wdf,
               float* __restrict__ part) {
  __shared__ float red[8 * RSTR];           // 16.5 KB — the ONLY LDS

  const int tid  = threadIdx.x;
  // XCD swizzle: the 6 c_blks of one b land on the same id%8 slot.
  const int id    = blockIdx.x;     // 0..3071
  const int slot  = id & 7;
  const int t8    = id >> 3;        // 0..383
  const int c_blk = t8 % 6;
  const int b     = (t8 / 6) * 8 + slot;

  const int lane  = tid & 63;
  const int wv    = tid >> 6;          // 4 waves; wave owns ONE 16-c fragment
  const int lrow  = lane & 15;
  const int lquad = lane >> 4;

  // ---- A-fragments DIRECT from global: 6 frags, f32x4 pairs, pack in-reg ----
  bf16x8 a[6];
  {
    const float* rp = x + ((size_t)b * C_ + (size_t)c_blk * CT_P + wv * 16 + lrow) * HW_;
    #pragma unroll
    for (int kb = 0; kb < 6; ++kb) {
      const int k0 = kb * 32 + lquad * 8;
      float v0, v1, v2, v3, v4, v5, v6, v7;
      if (kb < 5 || k0 + 7 < HW_) {          // kb<=4 always safe (max 159)
        f32x4u t0 = *(const f32x4u*)(rp + k0);
        f32x4u t1 = *(const f32x4u*)(rp + k0 + 4);
        v0 = t0[0]; v1 = t0[1]; v2 = t0[2]; v3 = t0[3];
        v4 = t1[0]; v5 = t1[1]; v6 = t1[2]; v7 = t1[3];
      } else {                               // kb==5 tail: col 168 then pad
        v0 = (k0 + 0 < HW_) ? rp[k0 + 0] : 0.f;
        v1 = v2 = v3 = v4 = v5 = v6 = v7 = 0.f;
      }
      u32x4 pk;
      pk.x = pack_trunc(v0, v1);
      pk.y = pack_trunc(v2, v3);
      pk.z = pack_trunc(v4, v5);
      pk.w = pack_trunc(v6, v7);
      a[kb] = __builtin_bit_cast(bf16x8, pk);
    }
  }

  const int cm0 = c_blk * 4 + wv;           // global 16-c fragment row (0..23)
  const __bf16* bb = wsf + (size_t)lane * 8;
  const float*  wb = wdf + (size_t)lane * 4;
  const f32x4 zero = {0.f, 0.f, 0.f, 0.f};
  // red row after quad-pair fold: wv*2 + (lquad>>1); lquad 0,2 write
  const int rrow = wv * 2 + (lquad >> 1);
  const bool wlane = ((lquad & 1) == 0);

  // ---- 32 n-fragments: 6 bfr + 1 wdf load, 6 MFMA, fold, one shfl ----
  #pragma unroll 1
  for (int nf = 0; nf < 32; ++nf) {
    bf16x8 bfr[6];
    #pragma unroll
    for (int kb = 0; kb < 6; ++kb)
      bfr[kb] = *(const bf16x8*)(bb + ((size_t)nf * 6 + kb) * 512);

    const f32x4 w = *(const f32x4*)(wb + (((size_t)cm0 * 32 + nf) * 256));

    f32x4 acc = zero;
    #pragma unroll
    for (int kb = 0; kb < 6; ++kb)
      acc = __builtin_amdgcn_mfma_f32_16x16x32_bf16(a[kb], bfr[kb], acc, 0, 0, 0);

    // fold acc * W_d (wdf C-layout, proven); lane covers 4 c of frag cm0
    float t = acc[0] * w[0] + acc[1] * w[1] + acc[2] * w[2] + acc[3] * w[3];
    t += __shfl_xor(t, 16, 64);             // fold lquad pairs (0,1),(2,3)
    if (wlane)
      red[rrow * RSTR + nf * 16 + lrow] = t;
  }
  __syncthreads();   // the ONLY barrier

  // ---- combine: 256 threads x 2 n; sum 8 red rows -> complete 64-c partial ----
  float* pb = part + ((size_t)c_blk * B_ + b) * N_;
  #pragma unroll
  for (int r = 0; r < 2; ++r) {
    const int n = r * 256 + tid;
    float v = 0.f;
    #pragma unroll
    for (int s = 0; s < 8; ++s)
      v += red[s * RSTR + n];
    pb[n] = v;
  }
}

// ---------------- reducer: out = sum of 6 slabs + bias ----------------
__global__ __launch_bounds__(256)
void reduce_part(const float* __restrict__ part,
                 const float* __restrict__ Wb,
                 float* __restrict__ out) {
  const size_t S = (size_t)B_ * N_;
  int idx = (blockIdx.x * 256 + threadIdx.x) * 4;   // 256 blocks -> covers 262144
  f32x4 wb = *(const f32x4u*)(Wb + (idx & (N_ - 1)));
  f32x4 r;
  #pragma unroll
  for (int i = 0; i < 4; ++i) r[i] = wb[i];
  #pragma unroll
  for (int s = 0; s < 6; ++s) {
    f32x4 a = *(const f32x4u*)(part + (size_t)s * S + idx);
    #pragma unroll
    for (int i = 0; i < 4; ++i) r[i] += a[i];
  }
  *(f32x4*)(out + idx) = r;
}

// ---------------- R8 main kernel (ws fits wsf+wdf only; 110 us proven) ----------------
__global__ __launch_bounds__(256, 3)
void conv_fused_v8(const float* __restrict__ x,
                   const __bf16* __restrict__ wsf,
                   const float* __restrict__ wdf,
                   const float* __restrict__ Wb,
                   float* __restrict__ out) {
  __shared__ __align__(16) __bf16 Xs[CT * SXR];   // 51.2 KB
  __shared__ float red[4][64];                     // 1 KB

  const int tid  = threadIdx.x;
  const int id    = blockIdx.x;     // 0..1535
  const int slot  = id & 7;
  const int t8    = id >> 3;        // 0..191
  const int c_blk = t8 % 3;
  const int b     = (t8 / 3) * 8 + slot;

  const int lane  = tid & 63;
  const int wv    = tid >> 6;          // 4 waves: 2x2 (c,n) 64x64 quadrants
  const int cq    = (wv >> 1) * 64;
  const int nq    = (wv & 1) * 64;
  const int lrow  = lane & 15;
  const int lquad = lane >> 4;

  const float* src = x + ((size_t)b * C_ + (size_t)c_blk * CT) * HW_;
  #pragma unroll 4
  for (int p = 0; p < 24; ++p) {
    int i   = p * 256 + tid;
    int row = i / 48;
    int ch  = i - row * 48;
    const float* bp = src + row * HW_ + ch * 4;
    float v0 = 0.f, v1 = 0.f, v2 = 0.f, v3 = 0.f;
    if (ch < 42) {
      f32x4u t = *(const f32x4u*)bp;
      v0 = t[0]; v1 = t[1]; v2 = t[2]; v3 = t[3];
    } else if (ch == 42) {
      v0 = bp[0];
    }
    unsigned d0 = pack_trunc(v0, v1);
    unsigned d1 = pack_trunc(v2, v3);
    uint2 d; d.x = d0; d.y = d1;
    *(uint2*)&Xs[row * SXR + ch * 4] = d;
  }
  __syncthreads();

  const int cm0 = c_blk * 8 + (cq >> 4);

  #pragma unroll 1
  for (int nb = 0; nb < 4; ++nb) {
    const int nm0 = nb * 8 + (nq >> 4);
    const __bf16* bbase = wsf + ((size_t)nm0 * 6) * 512 + (size_t)lane * 8;

    const f32x4 zero = {0.f, 0.f, 0.f, 0.f};
    f32x4 acc[4][4];
    #pragma unroll
    for (int mi = 0; mi < 4; ++mi)
      #pragma unroll
      for (int ni = 0; ni < 4; ++ni)
        acc[mi][ni] = zero;

    #pragma unroll
    for (int kb = 0; kb < 6; ++kb) {
      bf16x8 afr[4], bfr[4];
      #pragma unroll
      for (int mi = 0; mi < 4; ++mi)
        afr[mi] = *(const bf16x8*)&Xs[(cq + mi * 16 + lrow) * SXR + kb * 32 + lquad * 8];
      #pragma unroll
      for (int ni = 0; ni < 4; ++ni)
        bfr[ni] = *(const bf16x8*)(bbase + ((size_t)ni * 6 + kb) * 512);
      #pragma unroll
      for (int mi = 0; mi < 4; ++mi)
        #pragma unroll
        for (int ni = 0; ni < 4; ++ni)
          acc[mi][ni] = __builtin_amdgcn_mfma_f32_16x16x32_bf16(
              afr[mi], bfr[ni], acc[mi][ni], 0, 0, 0);
    }

    float s[4] = {0.f, 0.f, 0.f, 0.f};
    #pragma unroll
    for (int ni = 0; ni < 4; ++ni) {
      #pragma unroll
      for (int mi = 0; mi < 4; ++mi) {
        const f32x4 w = *(const f32x4*)(wdf +
            (((size_t)(cm0 + mi) * 32 + (nm0 + ni)) * 64 + lane) * 4);
        s[ni] += acc[mi][ni][0] * w[0] + acc[mi][ni][1] * w[1]
               + acc[mi][ni][2] * w[2] + acc[mi][ni][3] * w[3];
      }
    }

    #pragma unroll
    for (int ni = 0; ni < 4; ++ni) {
      s[ni] += __shfl_xor(s[ni], 16, 64);
      s[ni] += __shfl_xor(s[ni], 32, 64);
    }
    if (lane < 16) {
      #pragma unroll
      for (int ni = 0; ni < 4; ++ni)
        red[wv][ni * 16 + lrow] = s[ni];
    }
    __syncthreads();

    if (tid < 128) {
      const int half = tid >> 6;
      const int idx  = tid & 63;
      const int n    = nb * 128 + tid;
      float v = red[half][idx] + red[half + 2][idx];
      if (c_blk == 0) v += Wb[n];
      atomicAdd(&out[(size_t)b * N_ + n], v);
    }
    __syncthreads();
  }
}

// ---------------- fallback main kernel (no workspace needed) ----------------

#define LDSS 104
#define KCH  96
#define NT   128

__global__ __launch_bounds__(256)
void conv_main_fallback(const float* __restrict__ x,
                        const float* __restrict__ Ws_g,
                        const float* __restrict__ Wd,
                        const float* __restrict__ Wb,
                        float* __restrict__ out) {
  __shared__ __align__(16) __bf16 Xs[CT][LDSS];
  __shared__ __align__(16) __bf16 Ws[NT][LDSS];

  const int tid   = threadIdx.x;
  const int n_blk = blockIdx.x;
  const int c_blk = blockIdx.y;
  const int b     = blockIdx.z;
  const int c0 = c_blk * CT;
  const int n0 = n_blk * NT;
  const int lane  = tid & 63;
  const int wv    = tid >> 6;
  const int cq    = (wv >> 1) * 64;
  const int nq    = (wv & 1) * 64;
  const int lrow  = lane & 15;
  const int lquad = lane >> 4;

  const f32x4 zero = {0.f, 0.f, 0.f, 0.f};
  f32x4 acc[4][4];
  #pragma unroll
  for (int mi = 0; mi < 4; ++mi)
    #pragma unroll
    for (int ni = 0; ni < 4; ++ni)
      acc[mi][ni] = zero;

  const float* xb  = x    + (size_t)b  * (C_ * HW_) + (size_t)c0 * HW_;
  const float* wsb = Ws_g + (size_t)n0 * HW_;

  for (int ch = 0; ch < 2; ++ch) {
    const int k0 = ch * KCH;
    __syncthreads();
    for (int e = tid; e < CT * KCH; e += 256) {
      int r   = e / KCH;
      int col = e - r * KCH;
      int k   = k0 + col;
      float vx = 0.f, vw = 0.f;
      if (k < HW_) {
        vx = xb [r * HW_ + k];
        vw = wsb[r * HW_ + k];
      }
      Xs[r][col] = f2bf(vx);
      Ws[r][col] = f2bf(vw);
    }
    __syncthreads();

    #pragma unroll
    for (int ks = 0; ks < 3; ++ks) {
      const int kc = ks * 32 + lquad * 8;
      bf16x8 afr[4], bfr[4];
      #pragma unroll
      for (int mi = 0; mi < 4; ++mi)
        afr[mi] = *(const bf16x8*)&Xs[cq + mi * 16 + lrow][kc];
      #pragma unroll
      for (int ni = 0; ni < 4; ++ni)
        bfr[ni] = *(const bf16x8*)&Ws[nq + ni * 16 + lrow][kc];
      #pragma unroll
      for (int mi = 0; mi < 4; ++mi)
        #pragma unroll
        for (int ni = 0; ni < 4; ++ni)
          acc[mi][ni] = __builtin_amdgcn_mfma_f32_16x16x32_bf16(
              afr[mi], bfr[ni], acc[mi][ni], 0, 0, 0);
    }
  }

  #pragma unroll
  for (int ni = 0; ni < 4; ++ni) {
    const int n = n0 + nq + ni * 16 + lrow;
    float sv = 0.f;
    #pragma unroll
    for (int mi = 0; mi < 4; ++mi) {
      const int cbase = c0 + cq + mi * 16 + lquad * 4;
      #pragma unroll
      for (int i = 0; i < 4; ++i)
        sv += acc[mi][ni][i] * Wd[(size_t)n * C_ + (cbase + i)];
    }
    sv += __shfl_xor(sv, 16, 64);
    sv += __shfl_xor(sv, 32, 64);
    if (lane < 16) {
      if (c_blk == 0 && cq == 0) sv += Wb[n];
      atomicAdd(&out[(size_t)b * N_ + n], sv);
    }
  }
}

extern "C" void kernel_launch(void* const* d_in, const int* in_sizes, int n_in,
                              void* d_out, int out_size, void* d_ws, size_t ws_size,
                              hipStream_t stream) {
  const float* x   = (const float*)d_in[0];   // [512,384,13,13]
  const float* Wsp = (const float*)d_in[1];   // [512,13,13]
  const float* Wd  = (const float*)d_in[2];   // [512,384]
  const float* Wb  = (const float*)d_in[3];   // [1,512]
  float* out = (float*)d_out;                 // [512,512] fp32

  const size_t need_basic = WSF_ELEMS * sizeof(__bf16) + WDF_ELEMS * sizeof(float);
  const size_t need_full  = need_basic + PART_ELEMS * sizeof(float);

  if (ws_size >= need_full) {
    __bf16* wsf  = (__bf16*)d_ws;
    float*  wdf  = (float*)(wsf + WSF_ELEMS);
    float*  partb = wdf + WDF_ELEMS;

    prep_aux_kernel<<<240, 256, 0, stream>>>(Wsp, Wd, wsf, wdf);
    conv_part<<<3072, 256, 0, stream>>>(x, wsf, wdf, partb);
    reduce_part<<<256, 256, 0, stream>>>(partb, Wb, out);
  } else if (ws_size >= need_basic) {
    __bf16* wsf = (__bf16*)d_ws;
    float*  wdf = (float*)(wsf + WSF_ELEMS);

    hipMemsetAsync(d_out, 0, (size_t)out_size * sizeof(float), stream);
    prep_aux_kernel<<<240, 256, 0, stream>>>(Wsp, Wd, wsf, wdf);
    conv_fused_v8<<<1536, 256, 0, stream>>>(x, wsf, wdf, Wb, out);
  } else {
    hipMemsetAsync(d_out, 0, (size_t)out_size * sizeof(float), stream);
    dim3 grid(N_ / NT, C_ / CT, B_);
    conv_main_fallback<<<grid, 256, 0, stream>>>(x, Wsp, Wd, Wb, out);
  }
}

// Round 12
// 253.822 us; speedup vs baseline: 1.0707x; 1.0707x over previous
//
#include <hip/hip_runtime.h>

// out[b,n] = sum_{c,hw} x[b,c,hw] * W_s[n,hw] * W_d[n,c] + W_b[n]
// B=512, C=384, N=512, HW=169 (13x13).
//
// R20 = R17 + NON-TEMPORAL x loads / part stores. Single-variable experiment.
// Evidence chain: R18 (0.5x B-stream) = no change; R19 (2x occupancy, 2x
// B-stream) = WORSE (+33%); R8's LDS structure also ~110us. All structures
// pin at ~100us with every pipe <15% busy -> ~1200+ cy of stall per loop
// iteration = L2-MISS-class latency on the B-loads. Mechanism: x streams
// 133 MB through L2 (16.6 MB/XCD vs 4 MB L2), continuously evicting the
// wsf/wdf hot set (960 KB), so loop loads are served from L3/HBM latency.
// Fix: x has ZERO reuse (read once, straight to registers) -> load it
// nontemporal so it never displaces L2; part stores likewise.
// Base config = R17 verbatim: CT=128, grid 1536, launch_bounds(256,4),
// a[2][6] direct-load, fire-and-forget red writes, 3-slab part + reducer.
// Falsification: if dur unchanged +-5%, eviction theory dies; next step is
// LDS-staged B-chunks.

#define B_   512
#define C_   384
#define N_   512
#define HW_  169
#define CT   128     // c-tile rows (3 c_blks per b)
#define SXR  200     // Xs row stride (v8/fallback kernels)
#define RSTR 520     // red row stride in f32 (512 + 8 pad)

#define WSF_ELEMS  ((size_t)32 * 6 * 64 * 8)       // 98,304 bf16
#define WDF_ELEMS  ((size_t)24 * 32 * 64 * 4)      // 196,608 f32
#define PART_ELEMS ((size_t)3 * B_ * N_)           // 786,432 f32 (3 MB)

typedef __bf16 bf16x8 __attribute__((ext_vector_type(8)));
typedef float f32x4  __attribute__((ext_vector_type(4)));
typedef float f32x4u __attribute__((ext_vector_type(4), aligned(4)));
typedef unsigned u32x4 __attribute__((ext_vector_type(4)));

__device__ __forceinline__ __bf16 f2bf(float f) {
  union { float f; unsigned u; } v; v.f = f;
  unsigned r = (v.u + 0x7FFFu + ((v.u >> 16) & 1u)) >> 16;   // RNE
  unsigned short s = (unsigned short)r;
  return __builtin_bit_cast(__bf16, s);
}

// hi16(a)|hi16(b)<<16 : two bf16 truncations in one v_perm
__device__ __forceinline__ unsigned pack_trunc(float a, float b) {
  return __builtin_amdgcn_perm(__builtin_bit_cast(unsigned, b),
                               __builtin_bit_cast(unsigned, a), 0x07060302u);
}

// ---------------- prep_aux: wsf (B-frag order) + wdf (C-layout order) ----------------
__global__ __launch_bounds__(256)
void prep_aux_kernel(const float* __restrict__ Ws,
                     const float* __restrict__ Wd,
                     __bf16* __restrict__ wsf,
                     float* __restrict__ wdf) {
  int t = blockIdx.x * 256 + threadIdx.x;      // 61440 total, exact
  if (t < 12288) {
    // wsf: t = (nm*6 + kb)*64 + lane ; lane(q=l>>4,m=l&15) holds Ws[nm*16+m][kb*32+q*8+j]
    int lane = t & 63;
    int fr   = t >> 6;
    int kb   = fr % 6;
    int nm   = fr / 6;
    int n    = nm * 16 + (lane & 15);
    int k0   = kb * 32 + (lane >> 4) * 8;
    const float* src = Ws + (size_t)n * HW_;
    bf16x8 v;
    #pragma unroll
    for (int j = 0; j < 8; ++j) {
      int k = k0 + j;
      float f = (k < HW_) ? src[k] : 0.f;
      v[j] = f2bf(f);
    }
    *(bf16x8*)(wsf + (size_t)t * 8) = v;
  } else {
    // wdf: t2 = (cm*32 + nm)*64 + lane; elem i = Wd[nm*16+(l&15)][cm*16+(l>>4)*4+i]
    int t2 = t - 12288;
    int lane = t2 & 63;
    int fr   = t2 >> 6;
    int nm   = fr & 31;
    int cm   = fr >> 5;
    int n    = nm * 16 + (lane & 15);
    int c0   = cm * 16 + (lane >> 4) * 4;
    f32x4 w = *(const f32x4u*)(Wd + (size_t)n * C_ + c0);
    *(f32x4*)(wdf + (size_t)t2 * 4) = w;
  }
}

// ---------------- R20 main kernel: R17 + nontemporal x/part ----------------
__global__ __launch_bounds__(256, 4)       // 128-total band: 4 waves/SIMD
void conv_part(const float* __restrict__ x,
               const __bf16* __restrict__ wsf,
               const float* __restrict__ wdf,
               float* __restrict__ part) {
  __shared__ float red[16 * RSTR];          // 33.3 KB — the ONLY LDS

  const int tid  = threadIdx.x;
  // XCD swizzle: the 3 c_blks of one b land on the same id%8 slot.
  const int id    = blockIdx.x;     // 0..1535
  const int slot  = id & 7;
  const int t8    = id >> 3;        // 0..191
  const int c_blk = t8 % 3;
  const int b     = (t8 / 3) * 8 + slot;

  const int lane  = tid & 63;
  const int wv    = tid >> 6;          // 4 waves; wave owns 32 c-rows (2 frags)
  const int lrow  = lane & 15;
  const int lquad = lane >> 4;

  // ---- A-fragments DIRECT from global, NONTEMPORAL (x has zero reuse) ----
  bf16x8 a[2][6];
  #pragma unroll
  for (int mi = 0; mi < 2; ++mi) {
    const float* rp = x + ((size_t)b * C_ + (size_t)c_blk * CT + wv * 32 + mi * 16 + lrow) * HW_;
    #pragma unroll
    for (int kb = 0; kb < 6; ++kb) {
      const int k0 = kb * 32 + lquad * 8;
      float v0, v1, v2, v3, v4, v5, v6, v7;
      if (kb < 5 || k0 + 7 < HW_) {          // kb<=4 always safe (max 159)
        f32x4u t0 = __builtin_nontemporal_load((const f32x4u*)(rp + k0));
        f32x4u t1 = __builtin_nontemporal_load((const f32x4u*)(rp + k0 + 4));
        v0 = t0[0]; v1 = t0[1]; v2 = t0[2]; v3 = t0[3];
        v4 = t1[0]; v5 = t1[1]; v6 = t1[2]; v7 = t1[3];
      } else {                               // kb==5 tail: col 168 then pad
        v0 = (k0 + 0 < HW_) ? __builtin_nontemporal_load(rp + k0) : 0.f;
        v1 = v2 = v3 = v4 = v5 = v6 = v7 = 0.f;
      }
      u32x4 pk;
      pk.x = pack_trunc(v0, v1);
      pk.y = pack_trunc(v2, v3);
      pk.z = pack_trunc(v4, v5);
      pk.w = pack_trunc(v6, v7);
      a[mi][kb] = __builtin_bit_cast(bf16x8, pk);
    }
  }

  const int cm0 = c_blk * 8 + wv * 2;       // global 16-c fragment row (0..23)
  const __bf16* bb = wsf + (size_t)lane * 8;
  const float*  wb = wdf + (size_t)lane * 4;
  const f32x4 zero = {0.f, 0.f, 0.f, 0.f};
  // per-lane red slot: row = wv*4+lquad, col = nf*16+lrow
  float* rslot = red + (wv * 4 + lquad) * RSTR + lrow;

  // ---- 32 n-fragments: stream B from (now-unevicted) L2, MFMA, fold, write ----
  #pragma unroll 1
  for (int nf = 0; nf < 32; ++nf) {
    bf16x8 bfr[6];
    #pragma unroll
    for (int kb = 0; kb < 6; ++kb)
      bfr[kb] = *(const bf16x8*)(bb + ((size_t)nf * 6 + kb) * 512);

    f32x4 acc[2] = {zero, zero};
    #pragma unroll
    for (int kb = 0; kb < 6; ++kb)
      #pragma unroll
      for (int mi = 0; mi < 2; ++mi)
        acc[mi] = __builtin_amdgcn_mfma_f32_16x16x32_bf16(
            a[mi][kb], bfr[kb], acc[mi], 0, 0, 0);

    // fold acc * W_d (wdf C-layout, proven R7/R8 under CT=128)
    float t = 0.f;
    #pragma unroll
    for (int mi = 0; mi < 2; ++mi) {
      const f32x4 w = *(const f32x4*)(wb + (((size_t)(cm0 + mi) * 32 + nf) * 256));
      t += acc[mi][0] * w[0] + acc[mi][1] * w[1]
         + acc[mi][2] * w[2] + acc[mi][3] * w[3];
    }
    rslot[nf * 16] = t;                     // ds_write_b32, nothing waits on it
  }
  __syncthreads();   // the ONLY barrier

  // ---- combine: 256 threads x 2 n; sum 16 red rows; nontemporal store ----
  float* pb = part + ((size_t)c_blk * B_ + b) * N_;
  #pragma unroll
  for (int r = 0; r < 2; ++r) {
    const int n = r * 256 + tid;
    float v = 0.f;
    #pragma unroll
    for (int s = 0; s < 16; ++s)
      v += red[s * RSTR + n];
    __builtin_nontemporal_store(v, &pb[n]);
  }
}

// ---------------- reducer: out = sum of 3 slabs + bias ----------------
__global__ __launch_bounds__(256)
void reduce_part(const float* __restrict__ part,
                 const float* __restrict__ Wb,
                 float* __restrict__ out) {
  const size_t S = (size_t)B_ * N_;
  int idx = (blockIdx.x * 256 + threadIdx.x) * 4;   // 256 blocks -> covers 262144
  f32x4 a0 = *(const f32x4u*)(part + idx);
  f32x4 a1 = *(const f32x4u*)(part + S + idx);
  f32x4 a2 = *(const f32x4u*)(part + 2 * S + idx);
  f32x4 wb = *(const f32x4u*)(Wb + (idx & (N_ - 1)));
  f32x4 r;
  #pragma unroll
  for (int i = 0; i < 4; ++i)
    r[i] = a0[i] + a1[i] + a2[i] + wb[i];
  *(f32x4*)(out + idx) = r;
}

// ---------------- R8 main kernel (ws fits wsf+wdf only; 110 us proven) ----------------
__global__ __launch_bounds__(256, 3)
void conv_fused_v8(const float* __restrict__ x,
                   const __bf16* __restrict__ wsf,
                   const float* __restrict__ wdf,
                   const float* __restrict__ Wb,
                   float* __restrict__ out) {
  __shared__ __align__(16) __bf16 Xs[CT * SXR];   // 51.2 KB
  __shared__ float red[4][64];                     // 1 KB

  const int tid  = threadIdx.x;
  const int id    = blockIdx.x;     // 0..1535
  const int slot  = id & 7;
  const int t8    = id >> 3;        // 0..191
  const int c_blk = t8 % 3;
  const int b     = (t8 / 3) * 8 + slot;

  const int lane  = tid & 63;
  const int wv    = tid >> 6;          // 4 waves: 2x2 (c,n) 64x64 quadrants
  const int cq    = (wv >> 1) * 64;
  const int nq    = (wv & 1) * 64;
  const int lrow  = lane & 15;
  const int lquad = lane >> 4;

  const float* src = x + ((size_t)b * C_ + (size_t)c_blk * CT) * HW_;
  #pragma unroll 4
  for (int p = 0; p < 24; ++p) {
    int i   = p * 256 + tid;
    int row = i / 48;
    int ch  = i - row * 48;
    const float* bp = src + row * HW_ + ch * 4;
    float v0 = 0.f, v1 = 0.f, v2 = 0.f, v3 = 0.f;
    if (ch < 42) {
      f32x4u t = *(const f32x4u*)bp;
      v0 = t[0]; v1 = t[1]; v2 = t[2]; v3 = t[3];
    } else if (ch == 42) {
      v0 = bp[0];
    }
    unsigned d0 = pack_trunc(v0, v1);
    unsigned d1 = pack_trunc(v2, v3);
    uint2 d; d.x = d0; d.y = d1;
    *(uint2*)&Xs[row * SXR + ch * 4] = d;
  }
  __syncthreads();

  const int cm0 = c_blk * 8 + (cq >> 4);

  #pragma unroll 1
  for (int nb = 0; nb < 4; ++nb) {
    const int nm0 = nb * 8 + (nq >> 4);
    const __bf16* bbase = wsf + ((size_t)nm0 * 6) * 512 + (size_t)lane * 8;

    const f32x4 zero = {0.f, 0.f, 0.f, 0.f};
    f32x4 acc[4][4];
    #pragma unroll
    for (int mi = 0; mi < 4; ++mi)
      #pragma unroll
      for (int ni = 0; ni < 4; ++ni)
        acc[mi][ni] = zero;

    #pragma unroll
    for (int kb = 0; kb < 6; ++kb) {
      bf16x8 afr[4], bfr[4];
      #pragma unroll
      for (int mi = 0; mi < 4; ++mi)
        afr[mi] = *(const bf16x8*)&Xs[(cq + mi * 16 + lrow) * SXR + kb * 32 + lquad * 8];
      #pragma unroll
      for (int ni = 0; ni < 4; ++ni)
        bfr[ni] = *(const bf16x8*)(bbase + ((size_t)ni * 6 + kb) * 512);
      #pragma unroll
      for (int mi = 0; mi < 4; ++mi)
        #pragma unroll
        for (int ni = 0; ni < 4; ++ni)
          acc[mi][ni] = __builtin_amdgcn_mfma_f32_16x16x32_bf16(
              afr[mi], bfr[ni], acc[mi][ni], 0, 0, 0);
    }

    float s[4] = {0.f, 0.f, 0.f, 0.f};
    #pragma unroll
    for (int ni = 0; ni < 4; ++ni) {
      #pragma unroll
      for (int mi = 0; mi < 4; ++mi) {
        const f32x4 w = *(const f32x4*)(wdf +
            (((size_t)(cm0 + mi) * 32 + (nm0 + ni)) * 64 + lane) * 4);
        s[ni] += acc[mi][ni][0] * w[0] + acc[mi][ni][1] * w[1]
               + acc[mi][ni][2] * w[2] + acc[mi][ni][3] * w[3];
      }
    }

    #pragma unroll
    for (int ni = 0; ni < 4; ++ni) {
      s[ni] += __shfl_xor(s[ni], 16, 64);
      s[ni] += __shfl_xor(s[ni], 32, 64);
    }
    if (lane < 16) {
      #pragma unroll
      for (int ni = 0; ni < 4; ++ni)
        red[wv][ni * 16 + lrow] = s[ni];
    }
    __syncthreads();

    if (tid < 128) {
      const int half = tid >> 6;
      const int idx  = tid & 63;
      const int n    = nb * 128 + tid;
      float v = red[half][idx] + red[half + 2][idx];
      if (c_blk == 0) v += Wb[n];
      atomicAdd(&out[(size_t)b * N_ + n], v);
    }
    __syncthreads();
  }
}

// ---------------- fallback main kernel (no workspace needed) ----------------

#define LDSS 104
#define KCH  96
#define NT   128

__global__ __launch_bounds__(256)
void conv_main_fallback(const float* __restrict__ x,
                        const float* __restrict__ Ws_g,
                        const float* __restrict__ Wd,
                        const float* __restrict__ Wb,
                        float* __restrict__ out) {
  __shared__ __align__(16) __bf16 Xs[CT][LDSS];
  __shared__ __align__(16) __bf16 Ws[NT][LDSS];

  const int tid   = threadIdx.x;
  const int n_blk = blockIdx.x;
  const int c_blk = blockIdx.y;
  const int b     = blockIdx.z;
  const int c0 = c_blk * CT;
  const int n0 = n_blk * NT;
  const int lane  = tid & 63;
  const int wv    = tid >> 6;
  const int cq    = (wv >> 1) * 64;
  const int nq    = (wv & 1) * 64;
  const int lrow  = lane & 15;
  const int lquad = lane >> 4;

  const f32x4 zero = {0.f, 0.f, 0.f, 0.f};
  f32x4 acc[4][4];
  #pragma unroll
  for (int mi = 0; mi < 4; ++mi)
    #pragma unroll
    for (int ni = 0; ni < 4; ++ni)
      acc[mi][ni] = zero;

  const float* xb  = x    + (size_t)b  * (C_ * HW_) + (size_t)c0 * HW_;
  const float* wsb = Ws_g + (size_t)n0 * HW_;

  for (int ch = 0; ch < 2; ++ch) {
    const int k0 = ch * KCH;
    __syncthreads();
    for (int e = tid; e < CT * KCH; e += 256) {
      int r   = e / KCH;
      int col = e - r * KCH;
      int k   = k0 + col;
      float vx = 0.f, vw = 0.f;
      if (k < HW_) {
        vx = xb [r * HW_ + k];
        vw = wsb[r * HW_ + k];
      }
      Xs[r][col] = f2bf(vx);
      Ws[r][col] = f2bf(vw);
    }
    __syncthreads();

    #pragma unroll
    for (int ks = 0; ks < 3; ++ks) {
      const int kc = ks * 32 + lquad * 8;
      bf16x8 afr[4], bfr[4];
      #pragma unroll
      for (int mi = 0; mi < 4; ++mi)
        afr[mi] = *(const bf16x8*)&Xs[cq + mi * 16 + lrow][kc];
      #pragma unroll
      for (int ni = 0; ni < 4; ++ni)
        bfr[ni] = *(const bf16x8*)&Ws[nq + ni * 16 + lrow][kc];
      #pragma unroll
      for (int mi = 0; mi < 4; ++mi)
        #pragma unroll
        for (int ni = 0; ni < 4; ++ni)
          acc[mi][ni] = __builtin_amdgcn_mfma_f32_16x16x32_bf16(
              afr[mi], bfr[ni], acc[mi][ni], 0, 0, 0);
    }
  }

  #pragma unroll
  for (int ni = 0; ni < 4; ++ni) {
    const int n = n0 + nq + ni * 16 + lrow;
    float sv = 0.f;
    #pragma unroll
    for (int mi = 0; mi < 4; ++mi) {
      const int cbase = c0 + cq + mi * 16 + lquad * 4;
      #pragma unroll
      for (int i = 0; i < 4; ++i)
        sv += acc[mi][ni][i] * Wd[(size_t)n * C_ + (cbase + i)];
    }
    sv += __shfl_xor(sv, 16, 64);
    sv += __shfl_xor(sv, 32, 64);
    if (lane < 16) {
      if (c_blk == 0 && cq == 0) sv += Wb[n];
      atomicAdd(&out[(size_t)b * N_ + n], sv);
    }
  }
}

extern "C" void kernel_launch(void* const* d_in, const int* in_sizes, int n_in,
                              void* d_out, int out_size, void* d_ws, size_t ws_size,
                              hipStream_t stream) {
  const float* x   = (const float*)d_in[0];   // [512,384,13,13]
  const float* Wsp = (const float*)d_in[1];   // [512,13,13]
  const float* Wd  = (const float*)d_in[2];   // [512,384]
  const float* Wb  = (const float*)d_in[3];   // [1,512]
  float* out = (float*)d_out;                 // [512,512] fp32

  const size_t need_basic = WSF_ELEMS * sizeof(__bf16) + WDF_ELEMS * sizeof(float);
  const size_t need_full  = need_basic + PART_ELEMS * sizeof(float);

  if (ws_size >= need_full) {
    __bf16* wsf  = (__bf16*)d_ws;
    float*  wdf  = (float*)(wsf + WSF_ELEMS);
    float*  partb = wdf + WDF_ELEMS;

    prep_aux_kernel<<<240, 256, 0, stream>>>(Wsp, Wd, wsf, wdf);
    conv_part<<<1536, 256, 0, stream>>>(x, wsf, wdf, partb);
    reduce_part<<<256, 256, 0, stream>>>(partb, Wb, out);
  } else if (ws_size >= need_basic) {
    __bf16* wsf = (__bf16*)d_ws;
    float*  wdf = (float*)(wsf + WSF_ELEMS);

    hipMemsetAsync(d_out, 0, (size_t)out_size * sizeof(float), stream);
    prep_aux_kernel<<<240, 256, 0, stream>>>(Wsp, Wd, wsf, wdf);
    conv_fused_v8<<<1536, 256, 0, stream>>>(x, wsf, wdf, Wb, out);
  } else {
    hipMemsetAsync(d_out, 0, (size_t)out_size * sizeof(float), stream);
    dim3 grid(N_ / NT, C_ / CT, B_);
    conv_main_fallback<<<grid, 256, 0, stream>>>(x, Wsp, Wd, Wb, out);
  }
}

// Round 13
// 235.617 us; speedup vs baseline: 1.1534x; 1.0773x over previous
//
#include <hip/hip_runtime.h>

// out[b,n] = sum_{c,hw} x[b,c,hw] * W_s[n,hw] * W_d[n,c] + W_b[n]
// B=512, C=384, N=512, HW=169 (13x13).
//
// R21: every structural lever EXCEPT pipelining has been falsified:
// R18 (0.5x VMEM) 0Δ, R19 (2x occupancy) worse, R17 (no shfl tail) -4us,
// R20 (nontemporal) 0Δ. Counter arithmetic: ~1200cy wall per loop iteration,
// ~120cy busy -> ~1080cy exposed load latency, identical in every variant
// because MFMA operands are fed DIRECTLY by global loads in a serial
// {issue->vmcnt(0)->consume} iteration. Fix = m97 structure on the nf loop:
//  - 8 chunks x 4 nf; wsf B-frags double-buffered in LDS (2x24KB) staged by
//    global_load_lds(16B) for chunk c+1 WHILE computing chunk c from LDS.
//  - wdf loads for chunk c issued BEFORE the staging instructions, so the
//    fold's counted vmcnt doesn't drain the staging queue.
//  - 1 barrier/chunk (vmcnt drain lands after a full chunk of compute).
//  - Epilogue: R16-proven 2x shfl_xor + red[4][512] (8KB) + 4-way combine.
//  - LDS 56KB -> 2 blocks/CU; launch_bounds(256,2): LDS caps residency, so
//    request the 256-reg band = zero spill risk.
// Spill detector: WRITE_SIZE ~3MB. Expect occupancy ~25% BY DESIGN.

#define B_   512
#define C_   384
#define N_   512
#define HW_  169
#define CT   128     // c-tile rows (3 c_blks per b)
#define SXR  200     // Xs row stride (v8/fallback kernels)

#define WSF_ELEMS  ((size_t)32 * 6 * 64 * 8)       // 98,304 bf16 (192 KB)
#define WDF_ELEMS  ((size_t)24 * 32 * 64 * 4)      // 196,608 f32 (768 KB)
#define PART_ELEMS ((size_t)3 * B_ * N_)           // 786,432 f32 (3 MB)

typedef __bf16 bf16x8 __attribute__((ext_vector_type(8)));
typedef float f32x4  __attribute__((ext_vector_type(4)));
typedef float f32x4u __attribute__((ext_vector_type(4), aligned(4)));
typedef unsigned u32x4 __attribute__((ext_vector_type(4)));

__device__ __forceinline__ __bf16 f2bf(float f) {
  union { float f; unsigned u; } v; v.f = f;
  unsigned r = (v.u + 0x7FFFu + ((v.u >> 16) & 1u)) >> 16;   // RNE
  unsigned short s = (unsigned short)r;
  return __builtin_bit_cast(__bf16, s);
}

// hi16(a)|hi16(b)<<16 : two bf16 truncations in one v_perm
__device__ __forceinline__ unsigned pack_trunc(float a, float b) {
  return __builtin_amdgcn_perm(__builtin_bit_cast(unsigned, b),
                               __builtin_bit_cast(unsigned, a), 0x07060302u);
}

// async global->LDS, 16B per lane (wave-uniform LDS base + lane*16)
__device__ __forceinline__ void gload_lds16(const __bf16* g, __bf16* l) {
  __builtin_amdgcn_global_load_lds(
      (const __attribute__((address_space(1))) unsigned*)(g),
      (__attribute__((address_space(3))) unsigned*)(l),
      16, 0, 0);
}

// ---------------- prep_aux: wsf (B-frag order) + wdf (C-layout order) ----------------
__global__ __launch_bounds__(256)
void prep_aux_kernel(const float* __restrict__ Ws,
                     const float* __restrict__ Wd,
                     __bf16* __restrict__ wsf,
                     float* __restrict__ wdf) {
  int t = blockIdx.x * 256 + threadIdx.x;      // 61440 total, exact
  if (t < 12288) {
    // wsf: t = (nm*6 + kb)*64 + lane ; lane(q=l>>4,m=l&15) holds Ws[nm*16+m][kb*32+q*8+j]
    int lane = t & 63;
    int fr   = t >> 6;
    int kb   = fr % 6;
    int nm   = fr / 6;
    int n    = nm * 16 + (lane & 15);
    int k0   = kb * 32 + (lane >> 4) * 8;
    const float* src = Ws + (size_t)n * HW_;
    bf16x8 v;
    #pragma unroll
    for (int j = 0; j < 8; ++j) {
      int k = k0 + j;
      float f = (k < HW_) ? src[k] : 0.f;
      v[j] = f2bf(f);
    }
    *(bf16x8*)(wsf + (size_t)t * 8) = v;
  } else {
    // wdf: t2 = (cm*32 + nm)*64 + lane; elem i = Wd[nm*16+(l&15)][cm*16+(l>>4)*4+i]
    int t2 = t - 12288;
    int lane = t2 & 63;
    int fr   = t2 >> 6;
    int nm   = fr & 31;
    int cm   = fr >> 5;
    int n    = nm * 16 + (lane & 15);
    int c0   = cm * 16 + (lane >> 4) * 4;
    f32x4 w = *(const f32x4u*)(Wd + (size_t)n * C_ + c0);
    *(f32x4*)(wdf + (size_t)t2 * 4) = w;
  }
}

// ---------------- R21 main kernel: LDS-pipelined B-stream (m97 structure) ----------------
__global__ __launch_bounds__(256, 2)       // LDS caps at 2 blocks/CU; no reg pressure
void conv_part(const float* __restrict__ x,
               const __bf16* __restrict__ wsf,
               const float* __restrict__ wdf,
               float* __restrict__ part) {
  __shared__ __align__(16) __bf16 Bs[2][24 * 512];  // 2 x 24KB double buffer
  __shared__ float red[4 * 512];                    // 8 KB epilogue

  const int tid  = threadIdx.x;
  // XCD swizzle: the 3 c_blks of one b land on the same id%8 slot.
  const int id    = blockIdx.x;     // 0..1535
  const int slot  = id & 7;
  const int t8    = id >> 3;        // 0..191
  const int c_blk = t8 % 3;
  const int b     = (t8 / 3) * 8 + slot;

  const int lane  = tid & 63;
  const int wv    = tid >> 6;          // 4 waves; wave owns 32 c-rows (2 frags)
  const int lrow  = lane & 15;
  const int lquad = lane >> 4;

  // ---- A-fragments DIRECT from global: 12 frags, f32x4 pairs, pack in-reg ----
  bf16x8 a[2][6];
  #pragma unroll
  for (int mi = 0; mi < 2; ++mi) {
    const float* rp = x + ((size_t)b * C_ + (size_t)c_blk * CT + wv * 32 + mi * 16 + lrow) * HW_;
    #pragma unroll
    for (int kb = 0; kb < 6; ++kb) {
      const int k0 = kb * 32 + lquad * 8;
      float v0, v1, v2, v3, v4, v5, v6, v7;
      if (kb < 5 || k0 + 7 < HW_) {          // kb<=4 always safe (max 159)
        f32x4u t0 = *(const f32x4u*)(rp + k0);
        f32x4u t1 = *(const f32x4u*)(rp + k0 + 4);
        v0 = t0[0]; v1 = t0[1]; v2 = t0[2]; v3 = t0[3];
        v4 = t1[0]; v5 = t1[1]; v6 = t1[2]; v7 = t1[3];
      } else {                               // kb==5 tail: col 168 then pad
        v0 = (k0 + 0 < HW_) ? rp[k0 + 0] : 0.f;
        v1 = v2 = v3 = v4 = v5 = v6 = v7 = 0.f;
      }
      u32x4 pk;
      pk.x = pack_trunc(v0, v1);
      pk.y = pack_trunc(v2, v3);
      pk.z = pack_trunc(v4, v5);
      pk.w = pack_trunc(v6, v7);
      a[mi][kb] = __builtin_bit_cast(bf16x8, pk);
    }
  }

  const int cm0 = c_blk * 8 + wv * 2;       // global 16-c fragment row (0..23)
  const float* wb = wdf + (size_t)lane * 4;
  const f32x4 zero = {0.f, 0.f, 0.f, 0.f};
  float* rbase = red + wv * 512;

  // ---- prologue: stage chunk 0 (24 x 1KB fragments; 6 per wave) ----
  {
    const __bf16* g = wsf + ((size_t)(wv * 6) * 512) + (size_t)lane * 8;
    __bf16* l = &Bs[0][(wv * 6) * 512];
    #pragma unroll
    for (int j = 0; j < 6; ++j)
      gload_lds16(g + j * 512, l + j * 512);
  }
  __syncthreads();   // drain staging for chunk 0

  // ---- 8 chunks x 4 nf: compute from LDS while staging next chunk ----
  #pragma unroll 1
  for (int ch = 0; ch < 8; ++ch) {
    const int buf = ch & 1;

    // (1) wdf preload for THIS chunk — issued FIRST so the fold's counted
    //     vmcnt doesn't drain the staging queue issued below.
    f32x4 w[4][2];
    #pragma unroll
    for (int nfi = 0; nfi < 4; ++nfi)
      #pragma unroll
      for (int mi = 0; mi < 2; ++mi)
        w[nfi][mi] = *(const f32x4*)(wb +
            (((size_t)(cm0 + mi) * 32 + (ch * 4 + nfi)) * 256));

    // (2) stage NEXT chunk into the other buffer (no wait)
    if (ch < 7) {
      const __bf16* g = wsf + ((size_t)((ch + 1) * 24 + wv * 6) * 512) + (size_t)lane * 8;
      __bf16* l = &Bs[buf ^ 1][(wv * 6) * 512];
      #pragma unroll
      for (int j = 0; j < 6; ++j)
        gload_lds16(g + j * 512, l + j * 512);
    }

    // (3) compute 4 nf from the current LDS buffer
    #pragma unroll
    for (int nfi = 0; nfi < 4; ++nfi) {
      bf16x8 bfr[6];
      #pragma unroll
      for (int kb = 0; kb < 6; ++kb)
        bfr[kb] = *(const bf16x8*)&Bs[buf][(nfi * 6 + kb) * 512 + lane * 8];

      f32x4 acc[2] = {zero, zero};
      #pragma unroll
      for (int kb = 0; kb < 6; ++kb)
        #pragma unroll
        for (int mi = 0; mi < 2; ++mi)
          acc[mi] = __builtin_amdgcn_mfma_f32_16x16x32_bf16(
              a[mi][kb], bfr[kb], acc[mi], 0, 0, 0);

      float t = 0.f;
      #pragma unroll
      for (int mi = 0; mi < 2; ++mi)
        t += acc[mi][0] * w[nfi][mi][0] + acc[mi][1] * w[nfi][mi][1]
           + acc[mi][2] * w[nfi][mi][2] + acc[mi][3] * w[nfi][mi][3];
      // lanes {m,m+16,m+32,m+48} hold disjoint c-slices of the same n
      t += __shfl_xor(t, 16, 64);
      t += __shfl_xor(t, 32, 64);
      if (lane < 16)
        rbase[(ch * 4 + nfi) * 16 + lrow] = t;
    }

    __syncthreads();   // drains staging(ch+1); fences buf reuse
  }

  // ---- combine: 256 threads x 2 n -> complete partials, plain store ----
  float* pb = part + ((size_t)c_blk * B_ + b) * N_;
  #pragma unroll
  for (int r = 0; r < 2; ++r) {
    const int n = r * 256 + tid;
    float v = red[n] + red[512 + n] + red[1024 + n] + red[1536 + n];
    pb[n] = v;
  }
}

// ---------------- reducer: out = sum of 3 slabs + bias ----------------
__global__ __launch_bounds__(256)
void reduce_part(const float* __restrict__ part,
                 const float* __restrict__ Wb,
                 float* __restrict__ out) {
  const size_t S = (size_t)B_ * N_;
  int idx = (blockIdx.x * 256 + threadIdx.x) * 4;   // 256 blocks -> covers 262144
  f32x4 a0 = *(const f32x4u*)(part + idx);
  f32x4 a1 = *(const f32x4u*)(part + S + idx);
  f32x4 a2 = *(const f32x4u*)(part + 2 * S + idx);
  f32x4 wb = *(const f32x4u*)(Wb + (idx & (N_ - 1)));
  f32x4 r;
  #pragma unroll
  for (int i = 0; i < 4; ++i)
    r[i] = a0[i] + a1[i] + a2[i] + wb[i];
  *(f32x4*)(out + idx) = r;
}

// ---------------- R8 main kernel (ws fits wsf+wdf only; 110 us proven) ----------------
__global__ __launch_bounds__(256, 3)
void conv_fused_v8(const float* __restrict__ x,
                   const __bf16* __restrict__ wsf,
                   const float* __restrict__ wdf,
                   const float* __restrict__ Wb,
                   float* __restrict__ out) {
  __shared__ __align__(16) __bf16 Xs[CT * SXR];   // 51.2 KB
  __shared__ float red[4][64];                     // 1 KB

  const int tid  = threadIdx.x;
  const int id    = blockIdx.x;     // 0..1535
  const int slot  = id & 7;
  const int t8    = id >> 3;        // 0..191
  const int c_blk = t8 % 3;
  const int b     = (t8 / 3) * 8 + slot;

  const int lane  = tid & 63;
  const int wv    = tid >> 6;          // 4 waves: 2x2 (c,n) 64x64 quadrants
  const int cq    = (wv >> 1) * 64;
  const int nq    = (wv & 1) * 64;
  const int lrow  = lane & 15;
  const int lquad = lane >> 4;

  const float* src = x + ((size_t)b * C_ + (size_t)c_blk * CT) * HW_;
  #pragma unroll 4
  for (int p = 0; p < 24; ++p) {
    int i   = p * 256 + tid;
    int row = i / 48;
    int ch  = i - row * 48;
    const float* bp = src + row * HW_ + ch * 4;
    float v0 = 0.f, v1 = 0.f, v2 = 0.f, v3 = 0.f;
    if (ch < 42) {
      f32x4u t = *(const f32x4u*)bp;
      v0 = t[0]; v1 = t[1]; v2 = t[2]; v3 = t[3];
    } else if (ch == 42) {
      v0 = bp[0];
    }
    unsigned d0 = pack_trunc(v0, v1);
    unsigned d1 = pack_trunc(v2, v3);
    uint2 d; d.x = d0; d.y = d1;
    *(uint2*)&Xs[row * SXR + ch * 4] = d;
  }
  __syncthreads();

  const int cm0 = c_blk * 8 + (cq >> 4);

  #pragma unroll 1
  for (int nb = 0; nb < 4; ++nb) {
    const int nm0 = nb * 8 + (nq >> 4);
    const __bf16* bbase = wsf + ((size_t)nm0 * 6) * 512 + (size_t)lane * 8;

    const f32x4 zero = {0.f, 0.f, 0.f, 0.f};
    f32x4 acc[4][4];
    #pragma unroll
    for (int mi = 0; mi < 4; ++mi)
      #pragma unroll
      for (int ni = 0; ni < 4; ++ni)
        acc[mi][ni] = zero;

    #pragma unroll
    for (int kb = 0; kb < 6; ++kb) {
      bf16x8 afr[4], bfr[4];
      #pragma unroll
      for (int mi = 0; mi < 4; ++mi)
        afr[mi] = *(const bf16x8*)&Xs[(cq + mi * 16 + lrow) * SXR + kb * 32 + lquad * 8];
      #pragma unroll
      for (int ni = 0; ni < 4; ++ni)
        bfr[ni] = *(const bf16x8*)(bbase + ((size_t)ni * 6 + kb) * 512);
      #pragma unroll
      for (int mi = 0; mi < 4; ++mi)
        #pragma unroll
        for (int ni = 0; ni < 4; ++ni)
          acc[mi][ni] = __builtin_amdgcn_mfma_f32_16x16x32_bf16(
              afr[mi], bfr[ni], acc[mi][ni], 0, 0, 0);
    }

    float s[4] = {0.f, 0.f, 0.f, 0.f};
    #pragma unroll
    for (int ni = 0; ni < 4; ++ni) {
      #pragma unroll
      for (int mi = 0; mi < 4; ++mi) {
        const f32x4 w = *(const f32x4*)(wdf +
            (((size_t)(cm0 + mi) * 32 + (nm0 + ni)) * 64 + lane) * 4);
        s[ni] += acc[mi][ni][0] * w[0] + acc[mi][ni][1] * w[1]
               + acc[mi][ni][2] * w[2] + acc[mi][ni][3] * w[3];
      }
    }

    #pragma unroll
    for (int ni = 0; ni < 4; ++ni) {
      s[ni] += __shfl_xor(s[ni], 16, 64);
      s[ni] += __shfl_xor(s[ni], 32, 64);
    }
    if (lane < 16) {
      #pragma unroll
      for (int ni = 0; ni < 4; ++ni)
        red[wv][ni * 16 + lrow] = s[ni];
    }
    __syncthreads();

    if (tid < 128) {
      const int half = tid >> 6;
      const int idx  = tid & 63;
      const int n    = nb * 128 + tid;
      float v = red[half][idx] + red[half + 2][idx];
      if (c_blk == 0) v += Wb[n];
      atomicAdd(&out[(size_t)b * N_ + n], v);
    }
    __syncthreads();
  }
}

// ---------------- fallback main kernel (no workspace needed) ----------------

#define LDSS 104
#define KCH  96
#define NT   128

__global__ __launch_bounds__(256)
void conv_main_fallback(const float* __restrict__ x,
                        const float* __restrict__ Ws_g,
                        const float* __restrict__ Wd,
                        const float* __restrict__ Wb,
                        float* __restrict__ out) {
  __shared__ __align__(16) __bf16 Xs[CT][LDSS];
  __shared__ __align__(16) __bf16 Ws[NT][LDSS];

  const int tid   = threadIdx.x;
  const int n_blk = blockIdx.x;
  const int c_blk = blockIdx.y;
  const int b     = blockIdx.z;
  const int c0 = c_blk * CT;
  const int n0 = n_blk * NT;
  const int lane  = tid & 63;
  const int wv    = tid >> 6;
  const int cq    = (wv >> 1) * 64;
  const int nq    = (wv & 1) * 64;
  const int lrow  = lane & 15;
  const int lquad = lane >> 4;

  const f32x4 zero = {0.f, 0.f, 0.f, 0.f};
  f32x4 acc[4][4];
  #pragma unroll
  for (int mi = 0; mi < 4; ++mi)
    #pragma unroll
    for (int ni = 0; ni < 4; ++ni)
      acc[mi][ni] = zero;

  const float* xb  = x    + (size_t)b  * (C_ * HW_) + (size_t)c0 * HW_;
  const float* wsb = Ws_g + (size_t)n0 * HW_;

  for (int ch = 0; ch < 2; ++ch) {
    const int k0 = ch * KCH;
    __syncthreads();
    for (int e = tid; e < CT * KCH; e += 256) {
      int r   = e / KCH;
      int col = e - r * KCH;
      int k   = k0 + col;
      float vx = 0.f, vw = 0.f;
      if (k < HW_) {
        vx = xb [r * HW_ + k];
        vw = wsb[r * HW_ + k];
      }
      Xs[r][col] = f2bf(vx);
      Ws[r][col] = f2bf(vw);
    }
    __syncthreads();

    #pragma unroll
    for (int ks = 0; ks < 3; ++ks) {
      const int kc = ks * 32 + lquad * 8;
      bf16x8 afr[4], bfr[4];
      #pragma unroll
      for (int mi = 0; mi < 4; ++mi)
        afr[mi] = *(const bf16x8*)&Xs[cq + mi * 16 + lrow][kc];
      #pragma unroll
      for (int ni = 0; ni < 4; ++ni)
        bfr[ni] = *(const bf16x8*)&Ws[nq + ni * 16 + lrow][kc];
      #pragma unroll
      for (int mi = 0; mi < 4; ++mi)
        #pragma unroll
        for (int ni = 0; ni < 4; ++ni)
          acc[mi][ni] = __builtin_amdgcn_mfma_f32_16x16x32_bf16(
              afr[mi], bfr[ni], acc[mi][ni], 0, 0, 0);
    }
  }

  #pragma unroll
  for (int ni = 0; ni < 4; ++ni) {
    const int n = n0 + nq + ni * 16 + lrow;
    float sv = 0.f;
    #pragma unroll
    for (int mi = 0; mi < 4; ++mi) {
      const int cbase = c0 + cq + mi * 16 + lquad * 4;
      #pragma unroll
      for (int i = 0; i < 4; ++i)
        sv += acc[mi][ni][i] * Wd[(size_t)n * C_ + (cbase + i)];
    }
    sv += __shfl_xor(sv, 16, 64);
    sv += __shfl_xor(sv, 32, 64);
    if (lane < 16) {
      if (c_blk == 0 && cq == 0) sv += Wb[n];
      atomicAdd(&out[(size_t)b * N_ + n], sv);
    }
  }
}

extern "C" void kernel_launch(void* const* d_in, const int* in_sizes, int n_in,
                              void* d_out, int out_size, void* d_ws, size_t ws_size,
                              hipStream_t stream) {
  const float* x   = (const float*)d_in[0];   // [512,384,13,13]
  const float* Wsp = (const float*)d_in[1];   // [512,13,13]
  const float* Wd  = (const float*)d_in[2];   // [512,384]
  const float* Wb  = (const float*)d_in[3];   // [1,512]
  float* out = (float*)d_out;                 // [512,512] fp32

  const size_t need_basic = WSF_ELEMS * sizeof(__bf16) + WDF_ELEMS * sizeof(float);
  const size_t need_full  = need_basic + PART_ELEMS * sizeof(float);

  if (ws_size >= need_full) {
    __bf16* wsf  = (__bf16*)d_ws;
    float*  wdf  = (float*)(wsf + WSF_ELEMS);
    float*  partb = wdf + WDF_ELEMS;

    prep_aux_kernel<<<240, 256, 0, stream>>>(Wsp, Wd, wsf, wdf);
    conv_part<<<1536, 256, 0, stream>>>(x, wsf, wdf, partb);
    reduce_part<<<256, 256, 0, stream>>>(partb, Wb, out);
  } else if (ws_size >= need_basic) {
    __bf16* wsf = (__bf16*)d_ws;
    float*  wdf = (float*)(wsf + WSF_ELEMS);

    hipMemsetAsync(d_out, 0, (size_t)out_size * sizeof(float), stream);
    prep_aux_kernel<<<240, 256, 0, stream>>>(Wsp, Wd, wsf, wdf);
    conv_fused_v8<<<1536, 256, 0, stream>>>(x, wsf, wdf, Wb, out);
  } else {
    hipMemsetAsync(d_out, 0, (size_t)out_size * sizeof(float), stream);
    dim3 grid(N_ / NT, C_ / CT, B_);
    conv_main_fallback<<<grid, 256, 0, stream>>>(x, Wsp, Wd, Wb, out);
  }
}

// Round 14
// 227.299 us; speedup vs baseline: 1.1957x; 1.0366x over previous
//
#include <hip/hip_runtime.h>

// out[b,n] = sum_{c,hw} x[b,c,hw] * W_s[n,hw] * W_d[n,c] + W_b[n]
// B=512, C=384, N=512, HW=169 (13x13).
//
// R22 = R21 with chunk 4 -> 2 nf: trade pipeline depth for occupancy.
// R21 post-mortem: pipeline is the first structural win (102->94.4us), but
// LDS 57.3KB capped residency at 2 blocks/CU (occupancy 21%) so barrier
// drains + LDS latency had no TLP cover (MfmaUtil 16%, 360 TF effective).
// Fix: Bs = 2 x (12 frags = 12KB) + red 8KB = EXACTLY 32KB -> 5 blocks/CU,
// launch_bounds(256,5) (R21's 88 VGPR fits the 102-reg band). 16 chunks x
// {4 wdf preloads -> stage next chunk (3 frags/wave) -> 2 nf compute ->
// barrier}. 2x barriers, but 20 waves/CU hide each other's drains (m114
// wave-overlap). Everything else identical to R21.
// Detectors: WRITE ~3MB (spill), VGPR <=102, occupancy ~50-60%.

#define B_   512
#define C_   384
#define N_   512
#define HW_  169
#define CT   128     // c-tile rows (3 c_blks per b)
#define SXR  200     // Xs row stride (v8/fallback kernels)

#define WSF_ELEMS  ((size_t)32 * 6 * 64 * 8)       // 98,304 bf16 (192 KB)
#define WDF_ELEMS  ((size_t)24 * 32 * 64 * 4)      // 196,608 f32 (768 KB)
#define PART_ELEMS ((size_t)3 * B_ * N_)           // 786,432 f32 (3 MB)

typedef __bf16 bf16x8 __attribute__((ext_vector_type(8)));
typedef float f32x4  __attribute__((ext_vector_type(4)));
typedef float f32x4u __attribute__((ext_vector_type(4), aligned(4)));
typedef unsigned u32x4 __attribute__((ext_vector_type(4)));

__device__ __forceinline__ __bf16 f2bf(float f) {
  union { float f; unsigned u; } v; v.f = f;
  unsigned r = (v.u + 0x7FFFu + ((v.u >> 16) & 1u)) >> 16;   // RNE
  unsigned short s = (unsigned short)r;
  return __builtin_bit_cast(__bf16, s);
}

// hi16(a)|hi16(b)<<16 : two bf16 truncations in one v_perm
__device__ __forceinline__ unsigned pack_trunc(float a, float b) {
  return __builtin_amdgcn_perm(__builtin_bit_cast(unsigned, b),
                               __builtin_bit_cast(unsigned, a), 0x07060302u);
}

// async global->LDS, 16B per lane (wave-uniform LDS base + lane*16)
__device__ __forceinline__ void gload_lds16(const __bf16* g, __bf16* l) {
  __builtin_amdgcn_global_load_lds(
      (const __attribute__((address_space(1))) unsigned*)(g),
      (__attribute__((address_space(3))) unsigned*)(l),
      16, 0, 0);
}

// ---------------- prep_aux: wsf (B-frag order) + wdf (C-layout order) ----------------
__global__ __launch_bounds__(256)
void prep_aux_kernel(const float* __restrict__ Ws,
                     const float* __restrict__ Wd,
                     __bf16* __restrict__ wsf,
                     float* __restrict__ wdf) {
  int t = blockIdx.x * 256 + threadIdx.x;      // 61440 total, exact
  if (t < 12288) {
    // wsf: t = (nm*6 + kb)*64 + lane ; lane(q=l>>4,m=l&15) holds Ws[nm*16+m][kb*32+q*8+j]
    int lane = t & 63;
    int fr   = t >> 6;
    int kb   = fr % 6;
    int nm   = fr / 6;
    int n    = nm * 16 + (lane & 15);
    int k0   = kb * 32 + (lane >> 4) * 8;
    const float* src = Ws + (size_t)n * HW_;
    bf16x8 v;
    #pragma unroll
    for (int j = 0; j < 8; ++j) {
      int k = k0 + j;
      float f = (k < HW_) ? src[k] : 0.f;
      v[j] = f2bf(f);
    }
    *(bf16x8*)(wsf + (size_t)t * 8) = v;
  } else {
    // wdf: t2 = (cm*32 + nm)*64 + lane; elem i = Wd[nm*16+(l&15)][cm*16+(l>>4)*4+i]
    int t2 = t - 12288;
    int lane = t2 & 63;
    int fr   = t2 >> 6;
    int nm   = fr & 31;
    int cm   = fr >> 5;
    int n    = nm * 16 + (lane & 15);
    int c0   = cm * 16 + (lane >> 4) * 4;
    f32x4 w = *(const f32x4u*)(Wd + (size_t)n * C_ + c0);
    *(f32x4*)(wdf + (size_t)t2 * 4) = w;
  }
}

// ---------------- R22 main kernel: 2-nf chunks, 5 blocks/CU pipelined ----------------
__global__ __launch_bounds__(256, 5)       // ~85 regs -> 102-reg band; LDS 32KB = 5 blocks/CU
void conv_part(const float* __restrict__ x,
               const __bf16* __restrict__ wsf,
               const float* __restrict__ wdf,
               float* __restrict__ part) {
  __shared__ __align__(16) __bf16 Bs[2][12 * 512];  // 2 x 12KB double buffer
  __shared__ float red[4 * 512];                    // 8 KB epilogue -> 32KB total

  const int tid  = threadIdx.x;
  // XCD swizzle: the 3 c_blks of one b land on the same id%8 slot.
  const int id    = blockIdx.x;     // 0..1535
  const int slot  = id & 7;
  const int t8    = id >> 3;        // 0..191
  const int c_blk = t8 % 3;
  const int b     = (t8 / 3) * 8 + slot;

  const int lane  = tid & 63;
  const int wv    = tid >> 6;          // 4 waves; wave owns 32 c-rows (2 frags)
  const int lrow  = lane & 15;
  const int lquad = lane >> 4;

  // ---- A-fragments DIRECT from global: 12 frags, f32x4 pairs, pack in-reg ----
  bf16x8 a[2][6];
  #pragma unroll
  for (int mi = 0; mi < 2; ++mi) {
    const float* rp = x + ((size_t)b * C_ + (size_t)c_blk * CT + wv * 32 + mi * 16 + lrow) * HW_;
    #pragma unroll
    for (int kb = 0; kb < 6; ++kb) {
      const int k0 = kb * 32 + lquad * 8;
      float v0, v1, v2, v3, v4, v5, v6, v7;
      if (kb < 5 || k0 + 7 < HW_) {          // kb<=4 always safe (max 159)
        f32x4u t0 = *(const f32x4u*)(rp + k0);
        f32x4u t1 = *(const f32x4u*)(rp + k0 + 4);
        v0 = t0[0]; v1 = t0[1]; v2 = t0[2]; v3 = t0[3];
        v4 = t1[0]; v5 = t1[1]; v6 = t1[2]; v7 = t1[3];
      } else {                               // kb==5 tail: col 168 then pad
        v0 = (k0 + 0 < HW_) ? rp[k0 + 0] : 0.f;
        v1 = v2 = v3 = v4 = v5 = v6 = v7 = 0.f;
      }
      u32x4 pk;
      pk.x = pack_trunc(v0, v1);
      pk.y = pack_trunc(v2, v3);
      pk.z = pack_trunc(v4, v5);
      pk.w = pack_trunc(v6, v7);
      a[mi][kb] = __builtin_bit_cast(bf16x8, pk);
    }
  }

  const int cm0 = c_blk * 8 + wv * 2;       // global 16-c fragment row (0..23)
  const float* wb = wdf + (size_t)lane * 4;
  const f32x4 zero = {0.f, 0.f, 0.f, 0.f};
  float* rbase = red + wv * 512;

  // ---- prologue: stage chunk 0 (12 x 1KB fragments; 3 per wave) ----
  {
    const __bf16* g = wsf + ((size_t)(wv * 3) * 512) + (size_t)lane * 8;
    __bf16* l = &Bs[0][(wv * 3) * 512];
    #pragma unroll
    for (int j = 0; j < 3; ++j)
      gload_lds16(g + j * 512, l + j * 512);
  }
  __syncthreads();   // drain staging for chunk 0

  // ---- 16 chunks x 2 nf: compute from LDS while staging next chunk ----
  #pragma unroll 1
  for (int ch = 0; ch < 16; ++ch) {
    const int buf = ch & 1;

    // (1) wdf preload for THIS chunk — issued FIRST so the fold's counted
    //     vmcnt doesn't drain the staging queue issued below.
    f32x4 w[2][2];
    #pragma unroll
    for (int nfi = 0; nfi < 2; ++nfi)
      #pragma unroll
      for (int mi = 0; mi < 2; ++mi)
        w[nfi][mi] = *(const f32x4*)(wb +
            (((size_t)(cm0 + mi) * 32 + (ch * 2 + nfi)) * 256));

    // (2) stage NEXT chunk into the other buffer (no wait)
    if (ch < 15) {
      const __bf16* g = wsf + ((size_t)((ch + 1) * 12 + wv * 3) * 512) + (size_t)lane * 8;
      __bf16* l = &Bs[buf ^ 1][(wv * 3) * 512];
      #pragma unroll
      for (int j = 0; j < 3; ++j)
        gload_lds16(g + j * 512, l + j * 512);
    }

    // (3) compute 2 nf from the current LDS buffer
    #pragma unroll
    for (int nfi = 0; nfi < 2; ++nfi) {
      bf16x8 bfr[6];
      #pragma unroll
      for (int kb = 0; kb < 6; ++kb)
        bfr[kb] = *(const bf16x8*)&Bs[buf][(nfi * 6 + kb) * 512 + lane * 8];

      f32x4 acc[2] = {zero, zero};
      #pragma unroll
      for (int kb = 0; kb < 6; ++kb)
        #pragma unroll
        for (int mi = 0; mi < 2; ++mi)
          acc[mi] = __builtin_amdgcn_mfma_f32_16x16x32_bf16(
              a[mi][kb], bfr[kb], acc[mi], 0, 0, 0);

      float t = 0.f;
      #pragma unroll
      for (int mi = 0; mi < 2; ++mi)
        t += acc[mi][0] * w[nfi][mi][0] + acc[mi][1] * w[nfi][mi][1]
           + acc[mi][2] * w[nfi][mi][2] + acc[mi][3] * w[nfi][mi][3];
      // lanes {m,m+16,m+32,m+48} hold disjoint c-slices of the same n
      t += __shfl_xor(t, 16, 64);
      t += __shfl_xor(t, 32, 64);
      if (lane < 16)
        rbase[(ch * 2 + nfi) * 16 + lrow] = t;
    }

    __syncthreads();   // drains staging(ch+1); fences buf reuse
  }

  // ---- combine: 256 threads x 2 n -> complete partials, plain store ----
  float* pb = part + ((size_t)c_blk * B_ + b) * N_;
  #pragma unroll
  for (int r = 0; r < 2; ++r) {
    const int n = r * 256 + tid;
    float v = red[n] + red[512 + n] + red[1024 + n] + red[1536 + n];
    pb[n] = v;
  }
}

// ---------------- reducer: out = sum of 3 slabs + bias ----------------
__global__ __launch_bounds__(256)
void reduce_part(const float* __restrict__ part,
                 const float* __restrict__ Wb,
                 float* __restrict__ out) {
  const size_t S = (size_t)B_ * N_;
  int idx = (blockIdx.x * 256 + threadIdx.x) * 4;   // 256 blocks -> covers 262144
  f32x4 a0 = *(const f32x4u*)(part + idx);
  f32x4 a1 = *(const f32x4u*)(part + S + idx);
  f32x4 a2 = *(const f32x4u*)(part + 2 * S + idx);
  f32x4 wb = *(const f32x4u*)(Wb + (idx & (N_ - 1)));
  f32x4 r;
  #pragma unroll
  for (int i = 0; i < 4; ++i)
    r[i] = a0[i] + a1[i] + a2[i] + wb[i];
  *(f32x4*)(out + idx) = r;
}

// ---------------- R8 main kernel (ws fits wsf+wdf only; 110 us proven) ----------------
__global__ __launch_bounds__(256, 3)
void conv_fused_v8(const float* __restrict__ x,
                   const __bf16* __restrict__ wsf,
                   const float* __restrict__ wdf,
                   const float* __restrict__ Wb,
                   float* __restrict__ out) {
  __shared__ __align__(16) __bf16 Xs[CT * SXR];   // 51.2 KB
  __shared__ float red[4][64];                     // 1 KB

  const int tid  = threadIdx.x;
  const int id    = blockIdx.x;     // 0..1535
  const int slot  = id & 7;
  const int t8    = id >> 3;        // 0..191
  const int c_blk = t8 % 3;
  const int b     = (t8 / 3) * 8 + slot;

  const int lane  = tid & 63;
  const int wv    = tid >> 6;          // 4 waves: 2x2 (c,n) 64x64 quadrants
  const int cq    = (wv >> 1) * 64;
  const int nq    = (wv & 1) * 64;
  const int lrow  = lane & 15;
  const int lquad = lane >> 4;

  const float* src = x + ((size_t)b * C_ + (size_t)c_blk * CT) * HW_;
  #pragma unroll 4
  for (int p = 0; p < 24; ++p) {
    int i   = p * 256 + tid;
    int row = i / 48;
    int ch  = i - row * 48;
    const float* bp = src + row * HW_ + ch * 4;
    float v0 = 0.f, v1 = 0.f, v2 = 0.f, v3 = 0.f;
    if (ch < 42) {
      f32x4u t = *(const f32x4u*)bp;
      v0 = t[0]; v1 = t[1]; v2 = t[2]; v3 = t[3];
    } else if (ch == 42) {
      v0 = bp[0];
    }
    unsigned d0 = pack_trunc(v0, v1);
    unsigned d1 = pack_trunc(v2, v3);
    uint2 d; d.x = d0; d.y = d1;
    *(uint2*)&Xs[row * SXR + ch * 4] = d;
  }
  __syncthreads();

  const int cm0 = c_blk * 8 + (cq >> 4);

  #pragma unroll 1
  for (int nb = 0; nb < 4; ++nb) {
    const int nm0 = nb * 8 + (nq >> 4);
    const __bf16* bbase = wsf + ((size_t)nm0 * 6) * 512 + (size_t)lane * 8;

    const f32x4 zero = {0.f, 0.f, 0.f, 0.f};
    f32x4 acc[4][4];
    #pragma unroll
    for (int mi = 0; mi < 4; ++mi)
      #pragma unroll
      for (int ni = 0; ni < 4; ++ni)
        acc[mi][ni] = zero;

    #pragma unroll
    for (int kb = 0; kb < 6; ++kb) {
      bf16x8 afr[4], bfr[4];
      #pragma unroll
      for (int mi = 0; mi < 4; ++mi)
        afr[mi] = *(const bf16x8*)&Xs[(cq + mi * 16 + lrow) * SXR + kb * 32 + lquad * 8];
      #pragma unroll
      for (int ni = 0; ni < 4; ++ni)
        bfr[ni] = *(const bf16x8*)(bbase + ((size_t)ni * 6 + kb) * 512);
      #pragma unroll
      for (int mi = 0; mi < 4; ++mi)
        #pragma unroll
        for (int ni = 0; ni < 4; ++ni)
          acc[mi][ni] = __builtin_amdgcn_mfma_f32_16x16x32_bf16(
              afr[mi], bfr[ni], acc[mi][ni], 0, 0, 0);
    }

    float s[4] = {0.f, 0.f, 0.f, 0.f};
    #pragma unroll
    for (int ni = 0; ni < 4; ++ni) {
      #pragma unroll
      for (int mi = 0; mi < 4; ++mi) {
        const f32x4 w = *(const f32x4*)(wdf +
            (((size_t)(cm0 + mi) * 32 + (nm0 + ni)) * 64 + lane) * 4);
        s[ni] += acc[mi][ni][0] * w[0] + acc[mi][ni][1] * w[1]
               + acc[mi][ni][2] * w[2] + acc[mi][ni][3] * w[3];
      }
    }

    #pragma unroll
    for (int ni = 0; ni < 4; ++ni) {
      s[ni] += __shfl_xor(s[ni], 16, 64);
      s[ni] += __shfl_xor(s[ni], 32, 64);
    }
    if (lane < 16) {
      #pragma unroll
      for (int ni = 0; ni < 4; ++ni)
        red[wv][ni * 16 + lrow] = s[ni];
    }
    __syncthreads();

    if (tid < 128) {
      const int half = tid >> 6;
      const int idx  = tid & 63;
      const int n    = nb * 128 + tid;
      float v = red[half][idx] + red[half + 2][idx];
      if (c_blk == 0) v += Wb[n];
      atomicAdd(&out[(size_t)b * N_ + n], v);
    }
    __syncthreads();
  }
}

// ---------------- fallback main kernel (no workspace needed) ----------------

#define LDSS 104
#define KCH  96
#define NT   128

__global__ __launch_bounds__(256)
void conv_main_fallback(const float* __restrict__ x,
                        const float* __restrict__ Ws_g,
                        const float* __restrict__ Wd,
                        const float* __restrict__ Wb,
                        float* __restrict__ out) {
  __shared__ __align__(16) __bf16 Xs[CT][LDSS];
  __shared__ __align__(16) __bf16 Ws[NT][LDSS];

  const int tid   = threadIdx.x;
  const int n_blk = blockIdx.x;
  const int c_blk = blockIdx.y;
  const int b     = blockIdx.z;
  const int c0 = c_blk * CT;
  const int n0 = n_blk * NT;
  const int lane  = tid & 63;
  const int wv    = tid >> 6;
  const int cq    = (wv >> 1) * 64;
  const int nq    = (wv & 1) * 64;
  const int lrow  = lane & 15;
  const int lquad = lane >> 4;

  const f32x4 zero = {0.f, 0.f, 0.f, 0.f};
  f32x4 acc[4][4];
  #pragma unroll
  for (int mi = 0; mi < 4; ++mi)
    #pragma unroll
    for (int ni = 0; ni < 4; ++ni)
      acc[mi][ni] = zero;

  const float* xb  = x    + (size_t)b  * (C_ * HW_) + (size_t)c0 * HW_;
  const float* wsb = Ws_g + (size_t)n0 * HW_;

  for (int ch = 0; ch < 2; ++ch) {
    const int k0 = ch * KCH;
    __syncthreads();
    for (int e = tid; e < CT * KCH; e += 256) {
      int r   = e / KCH;
      int col = e - r * KCH;
      int k   = k0 + col;
      float vx = 0.f, vw = 0.f;
      if (k < HW_) {
        vx = xb [r * HW_ + k];
        vw = wsb[r * HW_ + k];
      }
      Xs[r][col] = f2bf(vx);
      Ws[r][col] = f2bf(vw);
    }
    __syncthreads();

    #pragma unroll
    for (int ks = 0; ks < 3; ++ks) {
      const int kc = ks * 32 + lquad * 8;
      bf16x8 afr[4], bfr[4];
      #pragma unroll
      for (int mi = 0; mi < 4; ++mi)
        afr[mi] = *(const bf16x8*)&Xs[cq + mi * 16 + lrow][kc];
      #pragma unroll
      for (int ni = 0; ni < 4; ++ni)
        bfr[ni] = *(const bf16x8*)&Ws[nq + ni * 16 + lrow][kc];
      #pragma unroll
      for (int mi = 0; mi < 4; ++mi)
        #pragma unroll
        for (int ni = 0; ni < 4; ++ni)
          acc[mi][ni] = __builtin_amdgcn_mfma_f32_16x16x32_bf16(
              afr[mi], bfr[ni], acc[mi][ni], 0, 0, 0);
    }
  }

  #pragma unroll
  for (int ni = 0; ni < 4; ++ni) {
    const int n = n0 + nq + ni * 16 + lrow;
    float sv = 0.f;
    #pragma unroll
    for (int mi = 0; mi < 4; ++mi) {
      const int cbase = c0 + cq + mi * 16 + lquad * 4;
      #pragma unroll
      for (int i = 0; i < 4; ++i)
        sv += acc[mi][ni][i] * Wd[(size_t)n * C_ + (cbase + i)];
    }
    sv += __shfl_xor(sv, 16, 64);
    sv += __shfl_xor(sv, 32, 64);
    if (lane < 16) {
      if (c_blk == 0 && cq == 0) sv += Wb[n];
      atomicAdd(&out[(size_t)b * N_ + n], sv);
    }
  }
}

extern "C" void kernel_launch(void* const* d_in, const int* in_sizes, int n_in,
                              void* d_out, int out_size, void* d_ws, size_t ws_size,
                              hipStream_t stream) {
  const float* x   = (const float*)d_in[0];   // [512,384,13,13]
  const float* Wsp = (const float*)d_in[1];   // [512,13,13]
  const float* Wd  = (const float*)d_in[2];   // [512,384]
  const float* Wb  = (const float*)d_in[3];   // [1,512]
  float* out = (float*)d_out;                 // [512,512] fp32

  const size_t need_basic = WSF_ELEMS * sizeof(__bf16) + WDF_ELEMS * sizeof(float);
  const size_t need_full  = need_basic + PART_ELEMS * sizeof(float);

  if (ws_size >= need_full) {
    __bf16* wsf  = (__bf16*)d_ws;
    float*  wdf  = (float*)(wsf + WSF_ELEMS);
    float*  partb = wdf + WDF_ELEMS;

    prep_aux_kernel<<<240, 256, 0, stream>>>(Wsp, Wd, wsf, wdf);
    conv_part<<<1536, 256, 0, stream>>>(x, wsf, wdf, partb);
    reduce_part<<<256, 256, 0, stream>>>(partb, Wb, out);
  } else if (ws_size >= need_basic) {
    __bf16* wsf = (__bf16*)d_ws;
    float*  wdf = (float*)(wsf + WSF_ELEMS);

    hipMemsetAsync(d_out, 0, (size_t)out_size * sizeof(float), stream);
    prep_aux_kernel<<<240, 256, 0, stream>>>(Wsp, Wd, wsf, wdf);
    conv_fused_v8<<<1536, 256, 0, stream>>>(x, wsf, wdf, Wb, out);
  } else {
    hipMemsetAsync(d_out, 0, (size_t)out_size * sizeof(float), stream);
    dim3 grid(N_ / NT, C_ / CT, B_);
    conv_main_fallback<<<grid, 256, 0, stream>>>(x, Wsp, Wd, Wb, out);
  }
}

// Round 15
// 225.038 us; speedup vs baseline: 1.2077x; 1.0100x over previous
//
#include <hip/hip_runtime.h>

// out[b,n] = sum_{c,hw} x[b,c,hw] * W_s[n,hw] * W_d[n,c] + W_b[n]
// B=512, C=384, N=512, HW=169 (13x13).
//
// R23 = R22 with honest register accounting.
// R22 post-mortem: dur 94.4->86.8 (pipeline works), but WRITE 9.2MB (6MB
// scratch spill) and occupancy 36% not 55%: true unified reg demand ~130
// (a=48 AGPR + bfr=24 + acc/w/addr) vs the forced 102-band -> spilled AND
// only ~3 blocks/CU effective. Fix: target the 128-band honestly:
//  - launch_bounds(256,4): 4 waves/SIMD, 4 blocks/CU at 32KB LDS.
//  - bfr[6] array removed: each B-frag ds_read inside the kb loop, live
//    one at a time, feeding both mi MFMAs (-16..20 regs -> ~105-110 total).
//  - Everything else identical to R22: 16 chunks x 2 nf, double-buffered
//    12KB Bs staged by global_load_lds(16B), wdf preloaded BEFORE staging,
//    1 barrier/chunk, shfl+red epilogue, 3-slab part + reducer, XCD swizzle.
// Detectors: WRITE must drop to ~3MB (spill gone); occupancy ~45-50%.

#define B_   512
#define C_   384
#define N_   512
#define HW_  169
#define CT   128     // c-tile rows (3 c_blks per b)
#define SXR  200     // Xs row stride (v8/fallback kernels)

#define WSF_ELEMS  ((size_t)32 * 6 * 64 * 8)       // 98,304 bf16 (192 KB)
#define WDF_ELEMS  ((size_t)24 * 32 * 64 * 4)      // 196,608 f32 (768 KB)
#define PART_ELEMS ((size_t)3 * B_ * N_)           // 786,432 f32 (3 MB)

typedef __bf16 bf16x8 __attribute__((ext_vector_type(8)));
typedef float f32x4  __attribute__((ext_vector_type(4)));
typedef float f32x4u __attribute__((ext_vector_type(4), aligned(4)));
typedef unsigned u32x4 __attribute__((ext_vector_type(4)));

__device__ __forceinline__ __bf16 f2bf(float f) {
  union { float f; unsigned u; } v; v.f = f;
  unsigned r = (v.u + 0x7FFFu + ((v.u >> 16) & 1u)) >> 16;   // RNE
  unsigned short s = (unsigned short)r;
  return __builtin_bit_cast(__bf16, s);
}

// hi16(a)|hi16(b)<<16 : two bf16 truncations in one v_perm
__device__ __forceinline__ unsigned pack_trunc(float a, float b) {
  return __builtin_amdgcn_perm(__builtin_bit_cast(unsigned, b),
                               __builtin_bit_cast(unsigned, a), 0x07060302u);
}

// async global->LDS, 16B per lane (wave-uniform LDS base + lane*16)
__device__ __forceinline__ void gload_lds16(const __bf16* g, __bf16* l) {
  __builtin_amdgcn_global_load_lds(
      (const __attribute__((address_space(1))) unsigned*)(g),
      (__attribute__((address_space(3))) unsigned*)(l),
      16, 0, 0);
}

// ---------------- prep_aux: wsf (B-frag order) + wdf (C-layout order) ----------------
__global__ __launch_bounds__(256)
void prep_aux_kernel(const float* __restrict__ Ws,
                     const float* __restrict__ Wd,
                     __bf16* __restrict__ wsf,
                     float* __restrict__ wdf) {
  int t = blockIdx.x * 256 + threadIdx.x;      // 61440 total, exact
  if (t < 12288) {
    // wsf: t = (nm*6 + kb)*64 + lane ; lane(q=l>>4,m=l&15) holds Ws[nm*16+m][kb*32+q*8+j]
    int lane = t & 63;
    int fr   = t >> 6;
    int kb   = fr % 6;
    int nm   = fr / 6;
    int n    = nm * 16 + (lane & 15);
    int k0   = kb * 32 + (lane >> 4) * 8;
    const float* src = Ws + (size_t)n * HW_;
    bf16x8 v;
    #pragma unroll
    for (int j = 0; j < 8; ++j) {
      int k = k0 + j;
      float f = (k < HW_) ? src[k] : 0.f;
      v[j] = f2bf(f);
    }
    *(bf16x8*)(wsf + (size_t)t * 8) = v;
  } else {
    // wdf: t2 = (cm*32 + nm)*64 + lane; elem i = Wd[nm*16+(l&15)][cm*16+(l>>4)*4+i]
    int t2 = t - 12288;
    int lane = t2 & 63;
    int fr   = t2 >> 6;
    int nm   = fr & 31;
    int cm   = fr >> 5;
    int n    = nm * 16 + (lane & 15);
    int c0   = cm * 16 + (lane >> 4) * 4;
    f32x4 w = *(const f32x4u*)(Wd + (size_t)n * C_ + c0);
    *(f32x4*)(wdf + (size_t)t2 * 4) = w;
  }
}

// ---------------- R23 main kernel: 2-nf chunks, 4 blocks/CU, no spill ----------------
__global__ __launch_bounds__(256, 4)       // ~105-110 regs -> 128-band, 4 blocks/CU
void conv_part(const float* __restrict__ x,
               const __bf16* __restrict__ wsf,
               const float* __restrict__ wdf,
               float* __restrict__ part) {
  __shared__ __align__(16) __bf16 Bs[2][12 * 512];  // 2 x 12KB double buffer
  __shared__ float red[4 * 512];                    // 8 KB epilogue -> 32KB total

  const int tid  = threadIdx.x;
  // XCD swizzle: the 3 c_blks of one b land on the same id%8 slot.
  const int id    = blockIdx.x;     // 0..1535
  const int slot  = id & 7;
  const int t8    = id >> 3;        // 0..191
  const int c_blk = t8 % 3;
  const int b     = (t8 / 3) * 8 + slot;

  const int lane  = tid & 63;
  const int wv    = tid >> 6;          // 4 waves; wave owns 32 c-rows (2 frags)
  const int lrow  = lane & 15;
  const int lquad = lane >> 4;

  // ---- A-fragments DIRECT from global: 12 frags, f32x4 pairs, pack in-reg ----
  bf16x8 a[2][6];
  #pragma unroll
  for (int mi = 0; mi < 2; ++mi) {
    const float* rp = x + ((size_t)b * C_ + (size_t)c_blk * CT + wv * 32 + mi * 16 + lrow) * HW_;
    #pragma unroll
    for (int kb = 0; kb < 6; ++kb) {
      const int k0 = kb * 32 + lquad * 8;
      float v0, v1, v2, v3, v4, v5, v6, v7;
      if (kb < 5 || k0 + 7 < HW_) {          // kb<=4 always safe (max 159)
        f32x4u t0 = *(const f32x4u*)(rp + k0);
        f32x4u t1 = *(const f32x4u*)(rp + k0 + 4);
        v0 = t0[0]; v1 = t0[1]; v2 = t0[2]; v3 = t0[3];
        v4 = t1[0]; v5 = t1[1]; v6 = t1[2]; v7 = t1[3];
      } else {                               // kb==5 tail: col 168 then pad
        v0 = (k0 + 0 < HW_) ? rp[k0 + 0] : 0.f;
        v1 = v2 = v3 = v4 = v5 = v6 = v7 = 0.f;
      }
      u32x4 pk;
      pk.x = pack_trunc(v0, v1);
      pk.y = pack_trunc(v2, v3);
      pk.z = pack_trunc(v4, v5);
      pk.w = pack_trunc(v6, v7);
      a[mi][kb] = __builtin_bit_cast(bf16x8, pk);
    }
  }

  const int cm0 = c_blk * 8 + wv * 2;       // global 16-c fragment row (0..23)
  const float* wb = wdf + (size_t)lane * 4;
  const f32x4 zero = {0.f, 0.f, 0.f, 0.f};
  float* rbase = red + wv * 512;

  // ---- prologue: stage chunk 0 (12 x 1KB fragments; 3 per wave) ----
  {
    const __bf16* g = wsf + ((size_t)(wv * 3) * 512) + (size_t)lane * 8;
    __bf16* l = &Bs[0][(wv * 3) * 512];
    #pragma unroll
    for (int j = 0; j < 3; ++j)
      gload_lds16(g + j * 512, l + j * 512);
  }
  __syncthreads();   // drain staging for chunk 0

  // ---- 16 chunks x 2 nf: compute from LDS while staging next chunk ----
  #pragma unroll 1
  for (int ch = 0; ch < 16; ++ch) {
    const int buf = ch & 1;

    // (1) wdf preload for THIS chunk — issued FIRST so the fold's counted
    //     vmcnt doesn't drain the staging queue issued below.
    f32x4 w[2][2];
    #pragma unroll
    for (int nfi = 0; nfi < 2; ++nfi)
      #pragma unroll
      for (int mi = 0; mi < 2; ++mi)
        w[nfi][mi] = *(const f32x4*)(wb +
            (((size_t)(cm0 + mi) * 32 + (ch * 2 + nfi)) * 256));

    // (2) stage NEXT chunk into the other buffer (no wait)
    if (ch < 15) {
      const __bf16* g = wsf + ((size_t)((ch + 1) * 12 + wv * 3) * 512) + (size_t)lane * 8;
      __bf16* l = &Bs[buf ^ 1][(wv * 3) * 512];
      #pragma unroll
      for (int j = 0; j < 3; ++j)
        gload_lds16(g + j * 512, l + j * 512);
    }

    // (3) compute 2 nf from the current LDS buffer; bfr live one at a time
    #pragma unroll
    for (int nfi = 0; nfi < 2; ++nfi) {
      f32x4 acc[2] = {zero, zero};
      #pragma unroll
      for (int kb = 0; kb < 6; ++kb) {
        const bf16x8 bfr = *(const bf16x8*)&Bs[buf][(nfi * 6 + kb) * 512 + lane * 8];
        acc[0] = __builtin_amdgcn_mfma_f32_16x16x32_bf16(a[0][kb], bfr, acc[0], 0, 0, 0);
        acc[1] = __builtin_amdgcn_mfma_f32_16x16x32_bf16(a[1][kb], bfr, acc[1], 0, 0, 0);
      }

      float t = 0.f;
      #pragma unroll
      for (int mi = 0; mi < 2; ++mi)
        t += acc[mi][0] * w[nfi][mi][0] + acc[mi][1] * w[nfi][mi][1]
           + acc[mi][2] * w[nfi][mi][2] + acc[mi][3] * w[nfi][mi][3];
      // lanes {m,m+16,m+32,m+48} hold disjoint c-slices of the same n
      t += __shfl_xor(t, 16, 64);
      t += __shfl_xor(t, 32, 64);
      if (lane < 16)
        rbase[(ch * 2 + nfi) * 16 + lrow] = t;
    }

    __syncthreads();   // drains staging(ch+1); fences buf reuse
  }

  // ---- combine: 256 threads x 2 n -> complete partials, plain store ----
  float* pb = part + ((size_t)c_blk * B_ + b) * N_;
  #pragma unroll
  for (int r = 0; r < 2; ++r) {
    const int n = r * 256 + tid;
    float v = red[n] + red[512 + n] + red[1024 + n] + red[1536 + n];
    pb[n] = v;
  }
}

// ---------------- reducer: out = sum of 3 slabs + bias ----------------
__global__ __launch_bounds__(256)
void reduce_part(const float* __restrict__ part,
                 const float* __restrict__ Wb,
                 float* __restrict__ out) {
  const size_t S = (size_t)B_ * N_;
  int idx = (blockIdx.x * 256 + threadIdx.x) * 4;   // 256 blocks -> covers 262144
  f32x4 a0 = *(const f32x4u*)(part + idx);
  f32x4 a1 = *(const f32x4u*)(part + S + idx);
  f32x4 a2 = *(const f32x4u*)(part + 2 * S + idx);
  f32x4 wb = *(const f32x4u*)(Wb + (idx & (N_ - 1)));
  f32x4 r;
  #pragma unroll
  for (int i = 0; i < 4; ++i)
    r[i] = a0[i] + a1[i] + a2[i] + wb[i];
  *(f32x4*)(out + idx) = r;
}

// ---------------- R8 main kernel (ws fits wsf+wdf only; 110 us proven) ----------------
__global__ __launch_bounds__(256, 3)
void conv_fused_v8(const float* __restrict__ x,
                   const __bf16* __restrict__ wsf,
                   const float* __restrict__ wdf,
                   const float* __restrict__ Wb,
                   float* __restrict__ out) {
  __shared__ __align__(16) __bf16 Xs[CT * SXR];   // 51.2 KB
  __shared__ float red[4][64];                     // 1 KB

  const int tid  = threadIdx.x;
  const int id    = blockIdx.x;     // 0..1535
  const int slot  = id & 7;
  const int t8    = id >> 3;        // 0..191
  const int c_blk = t8 % 3;
  const int b     = (t8 / 3) * 8 + slot;

  const int lane  = tid & 63;
  const int wv    = tid >> 6;          // 4 waves: 2x2 (c,n) 64x64 quadrants
  const int cq    = (wv >> 1) * 64;
  const int nq    = (wv & 1) * 64;
  const int lrow  = lane & 15;
  const int lquad = lane >> 4;

  const float* src = x + ((size_t)b * C_ + (size_t)c_blk * CT) * HW_;
  #pragma unroll 4
  for (int p = 0; p < 24; ++p) {
    int i   = p * 256 + tid;
    int row = i / 48;
    int ch  = i - row * 48;
    const float* bp = src + row * HW_ + ch * 4;
    float v0 = 0.f, v1 = 0.f, v2 = 0.f, v3 = 0.f;
    if (ch < 42) {
      f32x4u t = *(const f32x4u*)bp;
      v0 = t[0]; v1 = t[1]; v2 = t[2]; v3 = t[3];
    } else if (ch == 42) {
      v0 = bp[0];
    }
    unsigned d0 = pack_trunc(v0, v1);
    unsigned d1 = pack_trunc(v2, v3);
    uint2 d; d.x = d0; d.y = d1;
    *(uint2*)&Xs[row * SXR + ch * 4] = d;
  }
  __syncthreads();

  const int cm0 = c_blk * 8 + (cq >> 4);

  #pragma unroll 1
  for (int nb = 0; nb < 4; ++nb) {
    const int nm0 = nb * 8 + (nq >> 4);
    const __bf16* bbase = wsf + ((size_t)nm0 * 6) * 512 + (size_t)lane * 8;

    const f32x4 zero = {0.f, 0.f, 0.f, 0.f};
    f32x4 acc[4][4];
    #pragma unroll
    for (int mi = 0; mi < 4; ++mi)
      #pragma unroll
      for (int ni = 0; ni < 4; ++ni)
        acc[mi][ni] = zero;

    #pragma unroll
    for (int kb = 0; kb < 6; ++kb) {
      bf16x8 afr[4], bfr[4];
      #pragma unroll
      for (int mi = 0; mi < 4; ++mi)
        afr[mi] = *(const bf16x8*)&Xs[(cq + mi * 16 + lrow) * SXR + kb * 32 + lquad * 8];
      #pragma unroll
      for (int ni = 0; ni < 4; ++ni)
        bfr[ni] = *(const bf16x8*)(bbase + ((size_t)ni * 6 + kb) * 512);
      #pragma unroll
      for (int mi = 0; mi < 4; ++mi)
        #pragma unroll
        for (int ni = 0; ni < 4; ++ni)
          acc[mi][ni] = __builtin_amdgcn_mfma_f32_16x16x32_bf16(
              afr[mi], bfr[ni], acc[mi][ni], 0, 0, 0);
    }

    float s[4] = {0.f, 0.f, 0.f, 0.f};
    #pragma unroll
    for (int ni = 0; ni < 4; ++ni) {
      #pragma unroll
      for (int mi = 0; mi < 4; ++mi) {
        const f32x4 w = *(const f32x4*)(wdf +
            (((size_t)(cm0 + mi) * 32 + (nm0 + ni)) * 64 + lane) * 4);
        s[ni] += acc[mi][ni][0] * w[0] + acc[mi][ni][1] * w[1]
               + acc[mi][ni][2] * w[2] + acc[mi][ni][3] * w[3];
      }
    }

    #pragma unroll
    for (int ni = 0; ni < 4; ++ni) {
      s[ni] += __shfl_xor(s[ni], 16, 64);
      s[ni] += __shfl_xor(s[ni], 32, 64);
    }
    if (lane < 16) {
      #pragma unroll
      for (int ni = 0; ni < 4; ++ni)
        red[wv][ni * 16 + lrow] = s[ni];
    }
    __syncthreads();

    if (tid < 128) {
      const int half = tid >> 6;
      const int idx  = tid & 63;
      const int n    = nb * 128 + tid;
      float v = red[half][idx] + red[half + 2][idx];
      if (c_blk == 0) v += Wb[n];
      atomicAdd(&out[(size_t)b * N_ + n], v);
    }
    __syncthreads();
  }
}

// ---------------- fallback main kernel (no workspace needed) ----------------

#define LDSS 104
#define KCH  96
#define NT   128

__global__ __launch_bounds__(256)
void conv_main_fallback(const float* __restrict__ x,
                        const float* __restrict__ Ws_g,
                        const float* __restrict__ Wd,
                        const float* __restrict__ Wb,
                        float* __restrict__ out) {
  __shared__ __align__(16) __bf16 Xs[CT][LDSS];
  __shared__ __align__(16) __bf16 Ws[NT][LDSS];

  const int tid   = threadIdx.x;
  const int n_blk = blockIdx.x;
  const int c_blk = blockIdx.y;
  const int b     = blockIdx.z;
  const int c0 = c_blk * CT;
  const int n0 = n_blk * NT;
  const int lane  = tid & 63;
  const int wv    = tid >> 6;
  const int cq    = (wv >> 1) * 64;
  const int nq    = (wv & 1) * 64;
  const int lrow  = lane & 15;
  const int lquad = lane >> 4;

  const f32x4 zero = {0.f, 0.f, 0.f, 0.f};
  f32x4 acc[4][4];
  #pragma unroll
  for (int mi = 0; mi < 4; ++mi)
    #pragma unroll
    for (int ni = 0; ni < 4; ++ni)
      acc[mi][ni] = zero;

  const float* xb  = x    + (size_t)b  * (C_ * HW_) + (size_t)c0 * HW_;
  const float* wsb = Ws_g + (size_t)n0 * HW_;

  for (int ch = 0; ch < 2; ++ch) {
    const int k0 = ch * KCH;
    __syncthreads();
    for (int e = tid; e < CT * KCH; e += 256) {
      int r   = e / KCH;
      int col = e - r * KCH;
      int k   = k0 + col;
      float vx = 0.f, vw = 0.f;
      if (k < HW_) {
        vx = xb [r * HW_ + k];
        vw = wsb[r * HW_ + k];
      }
      Xs[r][col] = f2bf(vx);
      Ws[r][col] = f2bf(vw);
    }
    __syncthreads();

    #pragma unroll
    for (int ks = 0; ks < 3; ++ks) {
      const int kc = ks * 32 + lquad * 8;
      bf16x8 afr[4], bfr[4];
      #pragma unroll
      for (int mi = 0; mi < 4; ++mi)
        afr[mi] = *(const bf16x8*)&Xs[cq + mi * 16 + lrow][kc];
      #pragma unroll
      for (int ni = 0; ni < 4; ++ni)
        bfr[ni] = *(const bf16x8*)&Ws[nq + ni * 16 + lrow][kc];
      #pragma unroll
      for (int mi = 0; mi < 4; ++mi)
        #pragma unroll
        for (int ni = 0; ni < 4; ++ni)
          acc[mi][ni] = __builtin_amdgcn_mfma_f32_16x16x32_bf16(
              afr[mi], bfr[ni], acc[mi][ni], 0, 0, 0);
    }
  }

  #pragma unroll
  for (int ni = 0; ni < 4; ++ni) {
    const int n = n0 + nq + ni * 16 + lrow;
    float sv = 0.f;
    #pragma unroll
    for (int mi = 0; mi < 4; ++mi) {
      const int cbase = c0 + cq + mi * 16 + lquad * 4;
      #pragma unroll
      for (int i = 0; i < 4; ++i)
        sv += acc[mi][ni][i] * Wd[(size_t)n * C_ + (cbase + i)];
    }
    sv += __shfl_xor(sv, 16, 64);
    sv += __shfl_xor(sv, 32, 64);
    if (lane < 16) {
      if (c_blk == 0 && cq == 0) sv += Wb[n];
      atomicAdd(&out[(size_t)b * N_ + n], sv);
    }
  }
}

extern "C" void kernel_launch(void* const* d_in, const int* in_sizes, int n_in,
                              void* d_out, int out_size, void* d_ws, size_t ws_size,
                              hipStream_t stream) {
  const float* x   = (const float*)d_in[0];   // [512,384,13,13]
  const float* Wsp = (const float*)d_in[1];   // [512,13,13]
  const float* Wd  = (const float*)d_in[2];   // [512,384]
  const float* Wb  = (const float*)d_in[3];   // [1,512]
  float* out = (float*)d_out;                 // [512,512] fp32

  const size_t need_basic = WSF_ELEMS * sizeof(__bf16) + WDF_ELEMS * sizeof(float);
  const size_t need_full  = need_basic + PART_ELEMS * sizeof(float);

  if (ws_size >= need_full) {
    __bf16* wsf  = (__bf16*)d_ws;
    float*  wdf  = (float*)(wsf + WSF_ELEMS);
    float*  partb = wdf + WDF_ELEMS;

    prep_aux_kernel<<<240, 256, 0, stream>>>(Wsp, Wd, wsf, wdf);
    conv_part<<<1536, 256, 0, stream>>>(x, wsf, wdf, partb);
    reduce_part<<<256, 256, 0, stream>>>(partb, Wb, out);
  } else if (ws_size >= need_basic) {
    __bf16* wsf = (__bf16*)d_ws;
    float*  wdf = (float*)(wsf + WSF_ELEMS);

    hipMemsetAsync(d_out, 0, (size_t)out_size * sizeof(float), stream);
    prep_aux_kernel<<<240, 256, 0, stream>>>(Wsp, Wd, wsf, wdf);
    conv_fused_v8<<<1536, 256, 0, stream>>>(x, wsf, wdf, Wb, out);
  } else {
    hipMemsetAsync(d_out, 0, (size_t)out_size * sizeof(float), stream);
    dim3 grid(N_ / NT, C_ / CT, B_);
    conv_main_fallback<<<grid, 256, 0, stream>>>(x, Wsp, Wd, Wb, out);
  }
}